// Round 8
// baseline (1557.288 us; speedup 1.0000x reference)
//
#include <hip/hip_runtime.h>
#include <math.h>

#define H40   40
#define NG    120
#define FIN   257
#define KP    1280     // 80 dims * 16 (silu + 8 splines + 7 pad)
#define KGI   320      // 257 padded to 5*64
#define KB    8        // scan: steps per barrier batch

typedef float  f2v  __attribute__((ext_vector_type(2)));
typedef float  f4v  __attribute__((ext_vector_type(4)));
typedef short  bfv  __attribute__((ext_vector_type(8)));
typedef unsigned short u8v __attribute__((ext_vector_type(8)));
typedef unsigned short u4v __attribute__((ext_vector_type(4)));

__device__ __forceinline__ float sigm(float x) {
  return __builtin_amdgcn_rcpf(1.0f + __expf(-x));
}
__device__ __forceinline__ float tanh_fast(float x) {
  return 1.0f - 2.0f * __builtin_amdgcn_rcpf(1.0f + __expf(2.0f * x));
}
__device__ __forceinline__ unsigned short f2bf(float x) {
  unsigned u = __float_as_uint(x);
  return (unsigned short)((u + 0x7fffu + ((u >> 16) & 1u)) >> 16);
}
__device__ __forceinline__ float bf2f(unsigned short h) {
  return __uint_as_float(((unsigned)h) << 16);
}

// Cox-de Boor cubic B-spline bases on uniform grid g[j] = 0.4*(j-3) - 1
__device__ __forceinline__ void bspline8(float x, float* B) {
  float b0[11];
#pragma unroll
  for (int j = 0; j < 11; ++j) {
    float g0 = 0.4f * (float)(j - 3) - 1.0f;
    float g1 = 0.4f * (float)(j - 2) - 1.0f;
    b0[j] = (x >= g0 && x < g1) ? 1.0f : 0.0f;
  }
  float b1[10];
#pragma unroll
  for (int j = 0; j < 10; ++j) {
    float gj  = 0.4f * (float)(j - 3) - 1.0f;
    float gj2 = 0.4f * (float)(j - 1) - 1.0f;
    b1[j] = (x - gj) * 2.5f * b0[j] + (gj2 - x) * 2.5f * b0[j + 1];
  }
  float b2[9];
#pragma unroll
  for (int j = 0; j < 9; ++j) {
    float gj  = 0.4f * (float)(j - 3) - 1.0f;
    float gj3 = 0.4f * (float)(j)     - 1.0f;
    b2[j] = (x - gj) * 1.25f * b1[j] + (gj3 - x) * 1.25f * b1[j + 1];
  }
#pragma unroll
  for (int j = 0; j < 8; ++j) {
    float gj  = 0.4f * (float)(j - 3) - 1.0f;
    float gj4 = 0.4f * (float)(j + 1) - 1.0f;
    B[j] = (x - gj) * (1.0f / 1.2f) * b2[j] + (gj4 - x) * (1.0f / 1.2f) * b2[j + 1];
  }
}

// ---------------------------------------------------------------------------
// prep: pack KAN weights into hi/lo bf16 planes, k'' = d*16 + f
__global__ void prep_wkan(const float* __restrict__ base_w, const float* __restrict__ spline_w,
                          const float* __restrict__ scaler, unsigned short* __restrict__ Wh,
                          unsigned short* __restrict__ Wl, int N) {
  int idx = blockIdx.x * blockDim.x + threadIdx.x;
  if (idx >= N * 80) return;
  int o = idx / 80, d = idx - o * 80;
  float sc = scaler[idx];
  float vals[16];
  vals[0] = base_w[idx];
#pragma unroll
  for (int k = 0; k < 8; ++k) vals[1 + k] = spline_w[(size_t)idx * 8 + k] * sc;
#pragma unroll
  for (int k = 9; k < 16; ++k) vals[k] = 0.f;
  size_t base = (size_t)o * KP + d * 16;
#pragma unroll
  for (int f = 0; f < 16; ++f) {
    unsigned short h = f2bf(vals[f]);
    Wh[base + f] = h;
    Wl[base + f] = f2bf(vals[f] - bf2f(h));
  }
}

// prep: pack GRU input weights (fwd 0..119, bwd 120..239) into hi/lo planes, K padded 320
__global__ void prep_wgi(const float* __restrict__ wih_f0, const float* __restrict__ wih_b0,
                         unsigned short* __restrict__ Wh, unsigned short* __restrict__ Wl) {
  int idx = blockIdx.x * blockDim.x + threadIdx.x;
  if (idx >= 240 * KGI) return;
  int o = idx / KGI, k = idx - o * KGI;
  float v = 0.f;
  if (k < FIN) v = (o < NG) ? wih_f0[(size_t)o * FIN + k] : wih_b0[(size_t)(o - NG) * FIN + k];
  unsigned short h = f2bf(v);
  Wh[idx] = h;
  Wl[idx] = f2bf(v - bf2f(h));
}

// ---------------------------------------------------------------------------
// Phase A: Gi[M][240] = X[M][257] @ Wcat^T + bih, split-bf16 MFMA. BM=64, BN=128.
__global__ __launch_bounds__(256, 2) void gemm_gi_mfma(
    const float* __restrict__ X, const unsigned short* __restrict__ Wh,
    const unsigned short* __restrict__ Wl,
    const float* __restrict__ bih_f0, const float* __restrict__ bih_b0,
    float* __restrict__ Gi, int M) {
  __shared__ unsigned short Ah[64][72], Al[64][72];
  __shared__ unsigned short Bh[128][72], Bl[128][72];
  int tid = threadIdx.x;
  int m0 = blockIdx.x * 64, o0 = blockIdx.y * 128;
  int wv = tid >> 6, lane = tid & 63;
  int lr = lane & 15, lkq = lane >> 4;

  f4v acc[8];
#pragma unroll
  for (int i = 0; i < 8; ++i) acc[i] = (f4v){0.f, 0.f, 0.f, 0.f};

  for (int c = 0; c < 5; ++c) {
#pragma unroll
    for (int i = 0; i < 4; ++i) {   // A: 64 rows x 16 quad-slots
      int s = tid + i * 256;
      int rr = s >> 4, q = s & 15;
      int m = m0 + rr, k = c * 64 + q * 4;
      float v0 = 0.f, v1 = 0.f, v2 = 0.f, v3 = 0.f;
      if (m < M) {
        const float* xp = X + (size_t)m * FIN;
        if (k < FIN)     v0 = xp[k];
        if (k + 1 < FIN) v1 = xp[k + 1];
        if (k + 2 < FIN) v2 = xp[k + 2];
        if (k + 3 < FIN) v3 = xp[k + 3];
      }
      u4v h, l;
      h[0] = f2bf(v0); l[0] = f2bf(v0 - bf2f(h[0]));
      h[1] = f2bf(v1); l[1] = f2bf(v1 - bf2f(h[1]));
      h[2] = f2bf(v2); l[2] = f2bf(v2 - bf2f(h[2]));
      h[3] = f2bf(v3); l[3] = f2bf(v3 - bf2f(h[3]));
      *(u4v*)&Ah[rr][q * 4] = h;
      *(u4v*)&Al[rr][q * 4] = l;
    }
#pragma unroll
    for (int i = 0; i < 4; ++i) {   // B: 128 cols x 8 oct-slots per plane
      int s = tid + i * 256;
      int col = s >> 3, kq = s & 7;
      int o = o0 + col;
      u8v wh = 0, wl = 0;
      if (o < 240) {
        size_t base = (size_t)o * KGI + c * 64 + kq * 8;
        wh = *(const u8v*)&Wh[base];
        wl = *(const u8v*)&Wl[base];
      }
      *(u8v*)&Bh[col][kq * 8] = wh;
      *(u8v*)&Bl[col][kq * 8] = wl;
    }
    __syncthreads();
#pragma unroll
    for (int s = 0; s < 2; ++s) {
      int kl = s * 32 + lkq * 8;
      bfv a_h = *(const bfv*)&Ah[wv * 16 + lr][kl];
      bfv a_l = *(const bfv*)&Al[wv * 16 + lr][kl];
#pragma unroll
      for (int cf = 0; cf < 8; ++cf) {
        bfv b_h = *(const bfv*)&Bh[cf * 16 + lr][kl];
        bfv b_l = *(const bfv*)&Bl[cf * 16 + lr][kl];
        acc[cf] = __builtin_amdgcn_mfma_f32_16x16x32_bf16(a_h, b_l, acc[cf], 0, 0, 0);
        acc[cf] = __builtin_amdgcn_mfma_f32_16x16x32_bf16(a_l, b_h, acc[cf], 0, 0, 0);
        acc[cf] = __builtin_amdgcn_mfma_f32_16x16x32_bf16(a_h, b_h, acc[cf], 0, 0, 0);
      }
    }
    __syncthreads();
  }
#pragma unroll
  for (int cf = 0; cf < 8; ++cf) {
    int o = o0 + cf * 16 + lr;
    if (o >= 240) continue;
    float bias = (o < NG) ? bih_f0[o] : bih_b0[o - NG];
#pragma unroll
    for (int e = 0; e < 4; ++e) {
      int m = m0 + wv * 16 + lkq * 4 + e;
      if (m < M) Gi[(size_t)m * 240 + o] = acc[cf][e] + bias;
    }
  }
}

// ---------------------------------------------------------------------------
// Phase C: KAN layer, split-bf16 MFMA, features built on the fly. BM=64, BN=64.
template <int FINAL>
__global__ __launch_bounds__(256, 2) void kan_mfma(
    const float* __restrict__ Z, const unsigned short* __restrict__ Wh,
    const unsigned short* __restrict__ Wl, const float* __restrict__ slope,
    float* __restrict__ Y, int M, int N) {
  __shared__ float zst[80 * 64];                 // transposed z tile [d][r]
  __shared__ unsigned short Fh[64][72], Fl[64][72];
  __shared__ unsigned short Bh[64][72], Bl[64][72];
  int tid = threadIdx.x;
  int m0 = blockIdx.x * 64, o0 = blockIdx.y * 64;
  int wv = tid >> 6, lane = tid & 63;
  int lr = lane & 15, lkq = lane >> 4;
  int r = tid & 63, dl = tid >> 6;

#pragma unroll
  for (int i = 0; i < 5; ++i) {                  // 64 rows x 20 float4 slots
    int s = tid + i * 256;
    int rr = s / 20, q = s - rr * 20;
    float4 v = make_float4(0.f, 0.f, 0.f, 0.f);
    int m = m0 + rr;
    if (m < M) v = *(const float4*)&Z[(size_t)m * 80 + q * 4];
    zst[(q * 4 + 0) * 64 + rr] = v.x;
    zst[(q * 4 + 1) * 64 + rr] = v.y;
    zst[(q * 4 + 2) * 64 + rr] = v.z;
    zst[(q * 4 + 3) * 64 + rr] = v.w;
  }
  __syncthreads();

  f4v acc[4];
#pragma unroll
  for (int i = 0; i < 4; ++i) acc[i] = (f4v){0.f, 0.f, 0.f, 0.f};

  for (int c = 0; c < 20; ++c) {
    {
      int d = c * 4 + dl;
      float z = zst[d * 64 + r];
      float f[16];
      f[0] = z * sigm(z);
      bspline8(z, &f[1]);
#pragma unroll
      for (int k = 9; k < 16; ++k) f[k] = 0.f;
      u8v h0, h1, l0, l1;
#pragma unroll
      for (int j = 0; j < 8; ++j) {
        unsigned short hh = f2bf(f[j]);
        h0[j] = hh; l0[j] = f2bf(f[j] - bf2f(hh));
        unsigned short hh2 = f2bf(f[8 + j]);
        h1[j] = hh2; l1[j] = f2bf(f[8 + j] - bf2f(hh2));
      }
      *(u8v*)&Fh[r][dl * 16] = h0;
      *(u8v*)&Fh[r][dl * 16 + 8] = h1;
      *(u8v*)&Fl[r][dl * 16] = l0;
      *(u8v*)&Fl[r][dl * 16 + 8] = l1;
    }
#pragma unroll
    for (int i = 0; i < 2; ++i) {                // W: 64 cols x 8 oct-slots
      int s = tid + i * 256;
      int col = s >> 3, kq = s & 7;
      int o = o0 + col;
      u8v wh = 0, wl = 0;
      if (o < N) {
        size_t base = (size_t)o * KP + c * 64 + kq * 8;
        wh = *(const u8v*)&Wh[base];
        wl = *(const u8v*)&Wl[base];
      }
      *(u8v*)&Bh[col][kq * 8] = wh;
      *(u8v*)&Bl[col][kq * 8] = wl;
    }
    __syncthreads();
#pragma unroll
    for (int s = 0; s < 2; ++s) {
      int kl = s * 32 + lkq * 8;
      bfv a_h = *(const bfv*)&Fh[wv * 16 + lr][kl];
      bfv a_l = *(const bfv*)&Fl[wv * 16 + lr][kl];
#pragma unroll
      for (int cf = 0; cf < 4; ++cf) {
        bfv b_h = *(const bfv*)&Bh[cf * 16 + lr][kl];
        bfv b_l = *(const bfv*)&Bl[cf * 16 + lr][kl];
        acc[cf] = __builtin_amdgcn_mfma_f32_16x16x32_bf16(a_h, b_l, acc[cf], 0, 0, 0);
        acc[cf] = __builtin_amdgcn_mfma_f32_16x16x32_bf16(a_l, b_h, acc[cf], 0, 0, 0);
        acc[cf] = __builtin_amdgcn_mfma_f32_16x16x32_bf16(a_h, b_h, acc[cf], 0, 0, 0);
      }
    }
    __syncthreads();
  }
#pragma unroll
  for (int cf = 0; cf < 4; ++cf) {
    int o = o0 + cf * 16 + lr;
    if (o >= N) continue;
    float sl = FINAL ? slope[o] : 0.f;
#pragma unroll
    for (int e = 0; e < 4; ++e) {
      int m = m0 + wv * 16 + lkq * 4 + e;
      if (m >= M) continue;
      float y = acc[cf][e];
      if (FINAL) y = 1.2f * sigm(sl * y);
      Y[(size_t)m * N + o] = y;
    }
  }
}

// ---------------------------------------------------------------------------
// Phase B scan helpers
__device__ __forceinline__ void load_row20(f2v* dst, const float* src) {
#pragma unroll
  for (int q = 0; q < 10; ++q) {
    f4v v = *(const f4v*)(src + 4 * q);
    dst[2 * q]     = __builtin_shufflevector(v, v, 0, 1);
    dst[2 * q + 1] = __builtin_shufflevector(v, v, 2, 3);
  }
}

__device__ __forceinline__ void dot3(const f2v* wr, const f2v* wz, const f2v* wn,
                                     const float* hrow, float& ar, float& az, float& an) {
  f2v a0 = {0.f, 0.f}, a1 = {0.f, 0.f}, a2 = {0.f, 0.f},
      a3 = {0.f, 0.f}, a4 = {0.f, 0.f}, a5 = {0.f, 0.f};
#pragma unroll
  for (int q = 0; q < 10; ++q) {
    f4v v = *(const f4v*)(hrow + 4 * q);
    f2v lo = __builtin_shufflevector(v, v, 0, 1);
    f2v hi = __builtin_shufflevector(v, v, 2, 3);
    a0 += wr[2 * q] * lo; a1 += wr[2 * q + 1] * hi;
    a2 += wz[2 * q] * lo; a3 += wz[2 * q + 1] * hi;
    a4 += wn[2 * q] * lo; a5 += wn[2 * q + 1] * hi;
  }
  ar = (a0.x + a0.y) + (a1.x + a1.y);
  az = (a2.x + a2.y) + (a3.x + a3.y);
  an = (a4.x + a4.y) + (a5.x + a5.y);
}

// Phase B: 128 chains, 3 waves/block, ONE __syncthreads per KB=8 steps.
// Lane j<40 owns gate rows {j,40+j,80+j} (in-lane act, no gathers).
// wave0: h0 recurrence for batch p (reads gih[p&1], in-wave LDS h0 bounce).
// wave1: gi prefetch for batch p+1 -> gih[(p+1)&1].
// wave2: si (wih1.h0) + h1 recurrence + output for batch p-1.
// GRU n-gate: h_n bias (bhh_n) multiplies by r: n = tanh(i_n + r*(whh_n.h + bhh_n)).
__global__ __launch_bounds__(192, 1) void scan_kernel(
    const float* __restrict__ Gi,
    const float* __restrict__ whh0f, const float* __restrict__ bhh0f,
    const float* __restrict__ wih1f, const float* __restrict__ whh1f,
    const float* __restrict__ bih1f, const float* __restrict__ bhh1f,
    const float* __restrict__ whh0b, const float* __restrict__ bhh0b,
    const float* __restrict__ wih1b, const float* __restrict__ whh1b,
    const float* __restrict__ bih1b, const float* __restrict__ bhh1b,
    float* __restrict__ out_cat, int B, int T) {
  int chain = blockIdx.x;
  int dir = (chain >= B) ? 1 : 0;
  int b = chain - dir * B;

  const float* whh0 = dir ? whh0b : whh0f;
  const float* bhh0 = dir ? bhh0b : bhh0f;
  const float* wih1 = dir ? wih1b : wih1f;
  const float* whh1 = dir ? whh1b : whh1f;
  const float* bih1 = dir ? bih1b : bih1f;
  const float* bhh1 = dir ? bhh1b : bhh1f;

  __shared__ __align__(16) float h0hist[2 * KB][40];
  __shared__ __align__(16) float gih[2][KB][120];
  __shared__ __align__(16) float h1buf[40];

  int tid = threadIdx.x;
  int wv = tid >> 6;
  int l = tid & 63;
  bool upd = (l < 40);
  int j = upd ? l : 39;

  // A-matrix: wave0 = whh0/bhh0; wave2 = wih1/bih1. B-matrix (wave2 only) = whh1/bhh1.
  const float* wA = (wv == 2) ? wih1 : whh0;
  const float* bA = (wv == 2) ? bih1 : bhh0;

  f2v wAr[20], wAz[20], wAn[20];
  f2v wBr[20], wBz[20], wBn[20];
  float bAr = 0.f, bAz = 0.f, bAn = 0.f;
  float bBr = 0.f, bBz = 0.f, bBn = 0.f;
  if (wv != 1) {
    load_row20(wAr, wA + (size_t)j * 40);
    load_row20(wAz, wA + (size_t)(40 + j) * 40);
    load_row20(wAn, wA + (size_t)(80 + j) * 40);
    bAr = bA[j]; bAz = bA[40 + j]; bAn = bA[80 + j];
  }
  if (wv == 2) {
    load_row20(wBr, whh1 + (size_t)j * 40);
    load_row20(wBz, whh1 + (size_t)(40 + j) * 40);
    load_row20(wBn, whh1 + (size_t)(80 + j) * 40);
    bBr = bhh1[j]; bBz = bhh1[40 + j]; bBn = bhh1[80 + j];
  }

  const float* gbase = Gi + (size_t)b * T * 240 + dir * 120;
  float h = 0.f;   // wave0: h0[j]; wave2: h1[j]
  int nbatch = (T + KB - 1) / KB;

  // prologue: zero h0_{-1} slot and h1; wave1 stages gi batch 0 into gih[0]
  if (tid < 40) h0hist[2 * KB - 1][tid] = 0.f;
  if (wv == 2 && upd) h1buf[j] = 0.f;
  if (wv == 1 && upd) {
#pragma unroll
    for (int kk = 0; kk < KB; ++kk) {
      int t = kk < T ? kk : T - 1;
      int tt = dir ? (T - 1 - t) : t;
      const float* pp = gbase + (size_t)tt * 240;
      gih[0][kk][j] = pp[j];
      gih[0][kk][40 + j] = pp[40 + j];
      gih[0][kk][80 + j] = pp[80 + j];
    }
  }
  __syncthreads();

  for (int p = 0; p <= nbatch; ++p) {
    if (wv == 0) {
      // ---- h0 recurrence for batch p ----
      if (p < nbatch) {
        float gr[KB], gz[KB], gn[KB];
        const float (*gp)[120] = gih[p & 1];
#pragma unroll
        for (int kk = 0; kk < KB; ++kk) {
          gr[kk] = gp[kk][j]; gz[kk] = gp[kk][40 + j]; gn[kk] = gp[kk][80 + j];
        }
#pragma unroll
        for (int kk = 0; kk < KB; ++kk) {
          int t = p * KB + kk;
          if (t < T) {
            const float* hrow = h0hist[(t + 2 * KB - 1) & (2 * KB - 1)];
            float ar, az, an;
            dot3(wAr, wAz, wAn, hrow, ar, az, an);
            float r = sigm(gr[kk] + bAr + ar);
            float z = sigm(gz[kk] + bAz + az);
            float n = tanh_fast(gn[kk] + r * (an + bAn));   // bhh0_n INSIDE r*(.)
            h = (1.f - z) * n + z * h;
            if (upd) h0hist[t & (2 * KB - 1)][j] = h;
          }
        }
      }
    } else if (wv == 1) {
      // ---- gi prefetch for batch p+1 ----
      if ((p + 1) < nbatch && upd) {
        float a[KB], c[KB], d[KB];
#pragma unroll
        for (int kk = 0; kk < KB; ++kk) {
          int t = (p + 1) * KB + kk; t = t < T ? t : T - 1;
          int tt = dir ? (T - 1 - t) : t;
          const float* pp = gbase + (size_t)tt * 240;
          a[kk] = pp[j]; c[kk] = pp[40 + j]; d[kk] = pp[80 + j];
        }
        float (*gp)[120] = gih[(p + 1) & 1];
#pragma unroll
        for (int kk = 0; kk < KB; ++kk) {
          gp[kk][j] = a[kk]; gp[kk][40 + j] = c[kk]; gp[kk][80 + j] = d[kk];
        }
      }
    } else {
      // ---- si + h1 recurrence + output for batch p-1 ----
      if (p >= 1) {
#pragma unroll
        for (int kk = 0; kk < KB; ++kk) {
          int t = (p - 1) * KB + kk;
          if (t < T) {
            const float* hrow = h0hist[t & (2 * KB - 1)];   // h0_t
            float ir, iz, inn;
            dot3(wAr, wAz, wAn, hrow, ir, iz, inn);         // wih1 . h0_t
            float hr, hz, hn;
            dot3(wBr, wBz, wBn, h1buf, hr, hz, hn);         // whh1 . h1_{t-1}
            float r = sigm(ir + bAr + hr + bBr);
            float z = sigm(iz + bAz + hz + bBz);
            float n = tanh_fast(inn + bAn + r * (hn + bBn));
            h = (1.f - z) * n + z * h;
            if (upd) {
              h1buf[j] = h;
              out_cat[((size_t)b * T + t) * 80 + dir * 40 + j] = h;
            }
          }
        }
      }
    }
    __syncthreads();
  }
}

// ---------------------------------------------------------------------------
extern "C" void kernel_launch(void* const* d_in, const int* in_sizes, int n_in,
                              void* d_out, int out_size, void* d_ws, size_t ws_size,
                              hipStream_t stream) {
  const float* x        = (const float*)d_in[0];
  const float* wih_f0   = (const float*)d_in[2];
  const float* whh_f0   = (const float*)d_in[3];
  const float* bih_f0   = (const float*)d_in[4];
  const float* bhh_f0   = (const float*)d_in[5];
  const float* wih_f1   = (const float*)d_in[6];
  const float* whh_f1   = (const float*)d_in[7];
  const float* bih_f1   = (const float*)d_in[8];
  const float* bhh_f1   = (const float*)d_in[9];
  const float* wih_b0   = (const float*)d_in[10];
  const float* whh_b0   = (const float*)d_in[11];
  const float* bih_b0   = (const float*)d_in[12];
  const float* bhh_b0   = (const float*)d_in[13];
  const float* wih_b1   = (const float*)d_in[14];
  const float* whh_b1   = (const float*)d_in[15];
  const float* bih_b1   = (const float*)d_in[16];
  const float* bhh_b1   = (const float*)d_in[17];
  const float* gl_base_w   = (const float*)d_in[18];
  const float* gl_spline_w = (const float*)d_in[19];
  const float* gl_scaler   = (const float*)d_in[20];
  const float* lin_base_w   = (const float*)d_in[21];
  const float* lin_spline_w = (const float*)d_in[22];
  const float* lin_scaler   = (const float*)d_in[23];
  const float* slope        = (const float*)d_in[24];

  int B = in_sizes[1];
  int T = in_sizes[0] / (B * FIN);
  int M = B * T;

  float* Gi = (float*)d_out;   // M*240 <= M*257, overwritten by final kernel
  char* ws = (char*)d_ws;
  size_t off = 0;
  float* cat = (float*)(ws + off); off += (size_t)M * 80 * 4;
  float* U   = (float*)(ws + off); off += (size_t)M * 80 * 4;
  unsigned short* Wh_gl  = (unsigned short*)(ws + off); off += (size_t)80 * KP * 2;
  unsigned short* Wl_gl  = (unsigned short*)(ws + off); off += (size_t)80 * KP * 2;
  unsigned short* Wh_lin = (unsigned short*)(ws + off); off += (size_t)FIN * KP * 2;
  unsigned short* Wl_lin = (unsigned short*)(ws + off); off += (size_t)FIN * KP * 2;
  unsigned short* Wh_gi  = (unsigned short*)(ws + off); off += (size_t)240 * KGI * 2;
  unsigned short* Wl_gi  = (unsigned short*)(ws + off); off += (size_t)240 * KGI * 2;
  (void)ws_size; (void)n_in; (void)out_size;

  prep_wkan<<<dim3((80 * 80 + 255) / 256), 256, 0, stream>>>(gl_base_w, gl_spline_w, gl_scaler, Wh_gl, Wl_gl, 80);
  prep_wkan<<<dim3((FIN * 80 + 255) / 256), 256, 0, stream>>>(lin_base_w, lin_spline_w, lin_scaler, Wh_lin, Wl_lin, FIN);
  prep_wgi<<<dim3((240 * KGI + 255) / 256), 256, 0, stream>>>(wih_f0, wih_b0, Wh_gi, Wl_gi);

  gemm_gi_mfma<<<dim3((M + 63) / 64, 2), 256, 0, stream>>>(x, Wh_gi, Wl_gi, bih_f0, bih_b0, Gi, M);

  scan_kernel<<<dim3(2 * B), 192, 0, stream>>>(Gi,
      whh_f0, bhh_f0, wih_f1, whh_f1, bih_f1, bhh_f1,
      whh_b0, bhh_b0, wih_b1, whh_b1, bih_b1, bhh_b1,
      cat, B, T);

  kan_mfma<0><<<dim3((M + 63) / 64, 2), 256, 0, stream>>>(cat, Wh_gl, Wl_gl, nullptr, U, M, 80);
  kan_mfma<1><<<dim3((M + 63) / 64, 5), 256, 0, stream>>>(U, Wh_lin, Wl_lin, slope, (float*)d_out, M, FIN);
}

// Round 9
// 998.316 us; speedup vs baseline: 1.5599x; 1.5599x over previous
//
#include <hip/hip_runtime.h>
#include <math.h>

#define H40   40
#define NG    120
#define FIN   257
#define KP    1280     // 80 dims * 16 (silu + 8 splines + 7 pad)
#define KGI   320      // 257 padded to 5*64
#define KB    8        // scan: steps per barrier batch

typedef float  f2v  __attribute__((ext_vector_type(2)));
typedef float  f4v  __attribute__((ext_vector_type(4)));
typedef short  bfv  __attribute__((ext_vector_type(8)));
typedef unsigned short u8v __attribute__((ext_vector_type(8)));
typedef unsigned short u4v __attribute__((ext_vector_type(4)));

__device__ __forceinline__ float sigm(float x) {
  return __builtin_amdgcn_rcpf(1.0f + __expf(-x));
}
__device__ __forceinline__ float tanh_fast(float x) {
  return 1.0f - 2.0f * __builtin_amdgcn_rcpf(1.0f + __expf(2.0f * x));
}
__device__ __forceinline__ unsigned short f2bf(float x) {
  unsigned u = __float_as_uint(x);
  return (unsigned short)((u + 0x7fffu + ((u >> 16) & 1u)) >> 16);
}
__device__ __forceinline__ float bf2f(unsigned short h) {
  return __uint_as_float(((unsigned)h) << 16);
}

// Cox-de Boor cubic B-spline bases on uniform grid g[j] = 0.4*(j-3) - 1
__device__ __forceinline__ void bspline8(float x, float* B) {
  float b0[11];
#pragma unroll
  for (int j = 0; j < 11; ++j) {
    float g0 = 0.4f * (float)(j - 3) - 1.0f;
    float g1 = 0.4f * (float)(j - 2) - 1.0f;
    b0[j] = (x >= g0 && x < g1) ? 1.0f : 0.0f;
  }
  float b1[10];
#pragma unroll
  for (int j = 0; j < 10; ++j) {
    float gj  = 0.4f * (float)(j - 3) - 1.0f;
    float gj2 = 0.4f * (float)(j - 1) - 1.0f;
    b1[j] = (x - gj) * 2.5f * b0[j] + (gj2 - x) * 2.5f * b0[j + 1];
  }
  float b2[9];
#pragma unroll
  for (int j = 0; j < 9; ++j) {
    float gj  = 0.4f * (float)(j - 3) - 1.0f;
    float gj3 = 0.4f * (float)(j)     - 1.0f;
    b2[j] = (x - gj) * 1.25f * b1[j] + (gj3 - x) * 1.25f * b1[j + 1];
  }
#pragma unroll
  for (int j = 0; j < 8; ++j) {
    float gj  = 0.4f * (float)(j - 3) - 1.0f;
    float gj4 = 0.4f * (float)(j + 1) - 1.0f;
    B[j] = (x - gj) * (1.0f / 1.2f) * b2[j] + (gj4 - x) * (1.0f / 1.2f) * b2[j + 1];
  }
}

// ---------------------------------------------------------------------------
// prep: pack KAN weights into hi/lo bf16 planes, k'' = d*16 + f
__global__ void prep_wkan(const float* __restrict__ base_w, const float* __restrict__ spline_w,
                          const float* __restrict__ scaler, unsigned short* __restrict__ Wh,
                          unsigned short* __restrict__ Wl, int N) {
  int idx = blockIdx.x * blockDim.x + threadIdx.x;
  if (idx >= N * 80) return;
  int o = idx / 80, d = idx - o * 80;
  float sc = scaler[idx];
  float vals[16];
  vals[0] = base_w[idx];
#pragma unroll
  for (int k = 0; k < 8; ++k) vals[1 + k] = spline_w[(size_t)idx * 8 + k] * sc;
#pragma unroll
  for (int k = 9; k < 16; ++k) vals[k] = 0.f;
  size_t base = (size_t)o * KP + d * 16;
#pragma unroll
  for (int f = 0; f < 16; ++f) {
    unsigned short h = f2bf(vals[f]);
    Wh[base + f] = h;
    Wl[base + f] = f2bf(vals[f] - bf2f(h));
  }
}

// prep: pack GRU input weights (fwd 0..119, bwd 120..239) into hi/lo planes, K padded 320
__global__ void prep_wgi(const float* __restrict__ wih_f0, const float* __restrict__ wih_b0,
                         unsigned short* __restrict__ Wh, unsigned short* __restrict__ Wl) {
  int idx = blockIdx.x * blockDim.x + threadIdx.x;
  if (idx >= 240 * KGI) return;
  int o = idx / KGI, k = idx - o * KGI;
  float v = 0.f;
  if (k < FIN) v = (o < NG) ? wih_f0[(size_t)o * FIN + k] : wih_b0[(size_t)(o - NG) * FIN + k];
  unsigned short h = f2bf(v);
  Wh[idx] = h;
  Wl[idx] = f2bf(v - bf2f(h));
}

// ---------------------------------------------------------------------------
// Phase A: Gi[M][240] = X[M][257] @ Wcat^T + bih, split-bf16 MFMA. BM=64, BN=128.
__global__ __launch_bounds__(256, 2) void gemm_gi_mfma(
    const float* __restrict__ X, const unsigned short* __restrict__ Wh,
    const unsigned short* __restrict__ Wl,
    const float* __restrict__ bih_f0, const float* __restrict__ bih_b0,
    float* __restrict__ Gi, int M) {
  __shared__ unsigned short Ah[64][72], Al[64][72];
  __shared__ unsigned short Bh[128][72], Bl[128][72];
  int tid = threadIdx.x;
  int m0 = blockIdx.x * 64, o0 = blockIdx.y * 128;
  int wv = tid >> 6, lane = tid & 63;
  int lr = lane & 15, lkq = lane >> 4;

  f4v acc[8];
#pragma unroll
  for (int i = 0; i < 8; ++i) acc[i] = (f4v){0.f, 0.f, 0.f, 0.f};

  for (int c = 0; c < 5; ++c) {
#pragma unroll
    for (int i = 0; i < 4; ++i) {   // A: 64 rows x 16 quad-slots
      int s = tid + i * 256;
      int rr = s >> 4, q = s & 15;
      int m = m0 + rr, k = c * 64 + q * 4;
      float v0 = 0.f, v1 = 0.f, v2 = 0.f, v3 = 0.f;
      if (m < M) {
        const float* xp = X + (size_t)m * FIN;
        if (k < FIN)     v0 = xp[k];
        if (k + 1 < FIN) v1 = xp[k + 1];
        if (k + 2 < FIN) v2 = xp[k + 2];
        if (k + 3 < FIN) v3 = xp[k + 3];
      }
      u4v h, l;
      h[0] = f2bf(v0); l[0] = f2bf(v0 - bf2f(h[0]));
      h[1] = f2bf(v1); l[1] = f2bf(v1 - bf2f(h[1]));
      h[2] = f2bf(v2); l[2] = f2bf(v2 - bf2f(h[2]));
      h[3] = f2bf(v3); l[3] = f2bf(v3 - bf2f(h[3]));
      *(u4v*)&Ah[rr][q * 4] = h;
      *(u4v*)&Al[rr][q * 4] = l;
    }
#pragma unroll
    for (int i = 0; i < 4; ++i) {   // B: 128 cols x 8 oct-slots per plane
      int s = tid + i * 256;
      int col = s >> 3, kq = s & 7;
      int o = o0 + col;
      u8v wh = 0, wl = 0;
      if (o < 240) {
        size_t base = (size_t)o * KGI + c * 64 + kq * 8;
        wh = *(const u8v*)&Wh[base];
        wl = *(const u8v*)&Wl[base];
      }
      *(u8v*)&Bh[col][kq * 8] = wh;
      *(u8v*)&Bl[col][kq * 8] = wl;
    }
    __syncthreads();
#pragma unroll
    for (int s = 0; s < 2; ++s) {
      int kl = s * 32 + lkq * 8;
      bfv a_h = *(const bfv*)&Ah[wv * 16 + lr][kl];
      bfv a_l = *(const bfv*)&Al[wv * 16 + lr][kl];
#pragma unroll
      for (int cf = 0; cf < 8; ++cf) {
        bfv b_h = *(const bfv*)&Bh[cf * 16 + lr][kl];
        bfv b_l = *(const bfv*)&Bl[cf * 16 + lr][kl];
        acc[cf] = __builtin_amdgcn_mfma_f32_16x16x32_bf16(a_h, b_l, acc[cf], 0, 0, 0);
        acc[cf] = __builtin_amdgcn_mfma_f32_16x16x32_bf16(a_l, b_h, acc[cf], 0, 0, 0);
        acc[cf] = __builtin_amdgcn_mfma_f32_16x16x32_bf16(a_h, b_h, acc[cf], 0, 0, 0);
      }
    }
    __syncthreads();
  }
#pragma unroll
  for (int cf = 0; cf < 8; ++cf) {
    int o = o0 + cf * 16 + lr;
    if (o >= 240) continue;
    float bias = (o < NG) ? bih_f0[o] : bih_b0[o - NG];
#pragma unroll
    for (int e = 0; e < 4; ++e) {
      int m = m0 + wv * 16 + lkq * 4 + e;
      if (m < M) Gi[(size_t)m * 240 + o] = acc[cf][e] + bias;
    }
  }
}

// ---------------------------------------------------------------------------
// Phase C: KAN layer, split-bf16 MFMA, features built on the fly. BM=64, BN=64.
template <int FINAL>
__global__ __launch_bounds__(256, 2) void kan_mfma(
    const float* __restrict__ Z, const unsigned short* __restrict__ Wh,
    const unsigned short* __restrict__ Wl, const float* __restrict__ slope,
    float* __restrict__ Y, int M, int N) {
  __shared__ float zst[80 * 64];                 // transposed z tile [d][r]
  __shared__ unsigned short Fh[64][72], Fl[64][72];
  __shared__ unsigned short Bh[64][72], Bl[64][72];
  int tid = threadIdx.x;
  int m0 = blockIdx.x * 64, o0 = blockIdx.y * 64;
  int wv = tid >> 6, lane = tid & 63;
  int lr = lane & 15, lkq = lane >> 4;
  int r = tid & 63, dl = tid >> 6;

#pragma unroll
  for (int i = 0; i < 5; ++i) {                  // 64 rows x 20 float4 slots
    int s = tid + i * 256;
    int rr = s / 20, q = s - rr * 20;
    float4 v = make_float4(0.f, 0.f, 0.f, 0.f);
    int m = m0 + rr;
    if (m < M) v = *(const float4*)&Z[(size_t)m * 80 + q * 4];
    zst[(q * 4 + 0) * 64 + rr] = v.x;
    zst[(q * 4 + 1) * 64 + rr] = v.y;
    zst[(q * 4 + 2) * 64 + rr] = v.z;
    zst[(q * 4 + 3) * 64 + rr] = v.w;
  }
  __syncthreads();

  f4v acc[4];
#pragma unroll
  for (int i = 0; i < 4; ++i) acc[i] = (f4v){0.f, 0.f, 0.f, 0.f};

  for (int c = 0; c < 20; ++c) {
    {
      int d = c * 4 + dl;
      float z = zst[d * 64 + r];
      float f[16];
      f[0] = z * sigm(z);
      bspline8(z, &f[1]);
#pragma unroll
      for (int k = 9; k < 16; ++k) f[k] = 0.f;
      u8v h0, h1, l0, l1;
#pragma unroll
      for (int j = 0; j < 8; ++j) {
        unsigned short hh = f2bf(f[j]);
        h0[j] = hh; l0[j] = f2bf(f[j] - bf2f(hh));
        unsigned short hh2 = f2bf(f[8 + j]);
        h1[j] = hh2; l1[j] = f2bf(f[8 + j] - bf2f(hh2));
      }
      *(u8v*)&Fh[r][dl * 16] = h0;
      *(u8v*)&Fh[r][dl * 16 + 8] = h1;
      *(u8v*)&Fl[r][dl * 16] = l0;
      *(u8v*)&Fl[r][dl * 16 + 8] = l1;
    }
#pragma unroll
    for (int i = 0; i < 2; ++i) {                // W: 64 cols x 8 oct-slots
      int s = tid + i * 256;
      int col = s >> 3, kq = s & 7;
      int o = o0 + col;
      u8v wh = 0, wl = 0;
      if (o < N) {
        size_t base = (size_t)o * KP + c * 64 + kq * 8;
        wh = *(const u8v*)&Wh[base];
        wl = *(const u8v*)&Wl[base];
      }
      *(u8v*)&Bh[col][kq * 8] = wh;
      *(u8v*)&Bl[col][kq * 8] = wl;
    }
    __syncthreads();
#pragma unroll
    for (int s = 0; s < 2; ++s) {
      int kl = s * 32 + lkq * 8;
      bfv a_h = *(const bfv*)&Fh[wv * 16 + lr][kl];
      bfv a_l = *(const bfv*)&Fl[wv * 16 + lr][kl];
#pragma unroll
      for (int cf = 0; cf < 4; ++cf) {
        bfv b_h = *(const bfv*)&Bh[cf * 16 + lr][kl];
        bfv b_l = *(const bfv*)&Bl[cf * 16 + lr][kl];
        acc[cf] = __builtin_amdgcn_mfma_f32_16x16x32_bf16(a_h, b_l, acc[cf], 0, 0, 0);
        acc[cf] = __builtin_amdgcn_mfma_f32_16x16x32_bf16(a_l, b_h, acc[cf], 0, 0, 0);
        acc[cf] = __builtin_amdgcn_mfma_f32_16x16x32_bf16(a_h, b_h, acc[cf], 0, 0, 0);
      }
    }
    __syncthreads();
  }
#pragma unroll
  for (int cf = 0; cf < 4; ++cf) {
    int o = o0 + cf * 16 + lr;
    if (o >= N) continue;
    float sl = FINAL ? slope[o] : 0.f;
#pragma unroll
    for (int e = 0; e < 4; ++e) {
      int m = m0 + wv * 16 + lkq * 4 + e;
      if (m >= M) continue;
      float y = acc[cf][e];
      if (FINAL) y = 1.2f * sigm(sl * y);
      Y[(size_t)m * N + o] = y;
    }
  }
}

// ---------------------------------------------------------------------------
// Phase B scan helpers
__device__ __forceinline__ void load_row20(f2v* dst, const float* src) {
#pragma unroll
  for (int q = 0; q < 10; ++q) {
    f4v v = *(const f4v*)(src + 4 * q);
    dst[2 * q]     = __builtin_shufflevector(v, v, 0, 1);
    dst[2 * q + 1] = __builtin_shufflevector(v, v, 2, 3);
  }
}

__device__ __forceinline__ void dot3(const f2v* wr, const f2v* wz, const f2v* wn,
                                     const float* hrow, float& ar, float& az, float& an) {
  f2v a0 = {0.f, 0.f}, a1 = {0.f, 0.f}, a2 = {0.f, 0.f},
      a3 = {0.f, 0.f}, a4 = {0.f, 0.f}, a5 = {0.f, 0.f};
#pragma unroll
  for (int q = 0; q < 10; ++q) {
    f4v v = *(const f4v*)(hrow + 4 * q);
    f2v lo = __builtin_shufflevector(v, v, 0, 1);
    f2v hi = __builtin_shufflevector(v, v, 2, 3);
    a0 += wr[2 * q] * lo; a1 += wr[2 * q + 1] * hi;
    a2 += wz[2 * q] * lo; a3 += wz[2 * q + 1] * hi;
    a4 += wn[2 * q] * lo; a5 += wn[2 * q + 1] * hi;
  }
  ar = (a0.x + a0.y) + (a1.x + a1.y);
  az = (a2.x + a2.y) + (a3.x + a3.y);
  an = (a4.x + a4.y) + (a5.x + a5.y);
}

// Phase B: 128 chains, 3 waves/block, ONE __syncthreads per KB=8 steps.
// Each wave holds exactly ONE 120x40 weight matrix in registers (no spill):
//   wave0: whh0 -> h0 recurrence for batch p (reads gih[p&1]).
//   wave1: wih1 -> gi prefetch (batch p+1) + si = bih1 + wih1.h0 (batch p-1) -> sihist.
//   wave2: whh1 -> h1 recurrence + output (batch p-2, si from sihist).
// 16-slot histories = 2 batches so producer/consumer halves are disjoint.
__global__ __launch_bounds__(192, 1) void scan_kernel(
    const float* __restrict__ Gi,
    const float* __restrict__ whh0f, const float* __restrict__ bhh0f,
    const float* __restrict__ wih1f, const float* __restrict__ whh1f,
    const float* __restrict__ bih1f, const float* __restrict__ bhh1f,
    const float* __restrict__ whh0b, const float* __restrict__ bhh0b,
    const float* __restrict__ wih1b, const float* __restrict__ whh1b,
    const float* __restrict__ bih1b, const float* __restrict__ bhh1b,
    float* __restrict__ out_cat, int B, int T) {
  int chain = blockIdx.x;
  int dir = (chain >= B) ? 1 : 0;
  int b = chain - dir * B;

  const float* whh0 = dir ? whh0b : whh0f;
  const float* bhh0 = dir ? bhh0b : bhh0f;
  const float* wih1 = dir ? wih1b : wih1f;
  const float* whh1 = dir ? whh1b : whh1f;
  const float* bih1 = dir ? bih1b : bih1f;
  const float* bhh1 = dir ? bhh1b : bhh1f;

  __shared__ __align__(16) float h0hist[2 * KB][40];
  __shared__ __align__(16) float sihist[2 * KB][120];
  __shared__ __align__(16) float gih[2][KB][120];
  __shared__ __align__(16) float h1buf[40];

  int tid = threadIdx.x;
  int wv = tid >> 6;
  int l = tid & 63;
  bool upd = (l < 40);
  int j = upd ? l : 39;

  // ONE weight matrix per wave: w0=whh0/bhh0, w1=wih1/bih1, w2=whh1/bhh1.
  const float* wsel = (wv == 0) ? whh0 : (wv == 1) ? wih1 : whh1;
  const float* bsel = (wv == 0) ? bhh0 : (wv == 1) ? bih1 : bhh1;

  f2v wR[20], wZ[20], wN[20];
  load_row20(wR, wsel + (size_t)j * 40);
  load_row20(wZ, wsel + (size_t)(40 + j) * 40);
  load_row20(wN, wsel + (size_t)(80 + j) * 40);
  float bR = bsel[j], bZ = bsel[40 + j], bN = bsel[80 + j];

  const float* gbase = Gi + (size_t)b * T * 240 + dir * 120;
  float h = 0.f;   // wave0: h0[j]; wave2: h1[j]
  int nbatch = (T + KB - 1) / KB;

  // prologue: zero h0_{-1} slot and h1; wave1 stages gi batch 0 into gih[0]
  if (tid < 40) h0hist[2 * KB - 1][tid] = 0.f;
  if (wv == 2 && upd) h1buf[j] = 0.f;
  if (wv == 1 && upd) {
#pragma unroll
    for (int kk = 0; kk < KB; ++kk) {
      int t = kk < T ? kk : T - 1;
      int tt = dir ? (T - 1 - t) : t;
      const float* pp = gbase + (size_t)tt * 240;
      gih[0][kk][j] = pp[j];
      gih[0][kk][40 + j] = pp[40 + j];
      gih[0][kk][80 + j] = pp[80 + j];
    }
  }
  __syncthreads();

  for (int p = 0; p <= nbatch + 1; ++p) {
    if (wv == 0) {
      // ---- h0 recurrence for batch p ----
      if (p < nbatch) {
        float gr[KB], gz[KB], gn[KB];
        const float (*gp)[120] = gih[p & 1];
#pragma unroll
        for (int kk = 0; kk < KB; ++kk) {
          gr[kk] = gp[kk][j]; gz[kk] = gp[kk][40 + j]; gn[kk] = gp[kk][80 + j];
        }
#pragma unroll
        for (int kk = 0; kk < KB; ++kk) {
          int t = p * KB + kk;
          if (t < T) {
            const float* hrow = h0hist[(t + 2 * KB - 1) & (2 * KB - 1)];
            float ar, az, an;
            dot3(wR, wZ, wN, hrow, ar, az, an);
            float r = sigm(gr[kk] + bR + ar);
            float z = sigm(gz[kk] + bZ + az);
            float n = tanh_fast(gn[kk] + r * (an + bN));   // bhh0_n inside r*(.)
            h = (1.f - z) * n + z * h;
            if (upd) h0hist[t & (2 * KB - 1)][j] = h;
          }
        }
      }
    } else if (wv == 1) {
      // ---- gi prefetch (batch p+1) issued first for latency hiding ----
      float a[KB], c[KB], d[KB];
      bool havenext = (p + 1) < nbatch;
      if (havenext && upd) {
#pragma unroll
        for (int kk = 0; kk < KB; ++kk) {
          int t = (p + 1) * KB + kk; t = t < T ? t : T - 1;
          int tt = dir ? (T - 1 - t) : t;
          const float* pp = gbase + (size_t)tt * 240;
          a[kk] = pp[j]; c[kk] = pp[40 + j]; d[kk] = pp[80 + j];
        }
      }
      // ---- si for batch p-1 (h0hist written by wave0 last phase) ----
      if (p >= 1 && (p - 1) < nbatch) {
#pragma unroll
        for (int kk = 0; kk < KB; ++kk) {
          int t = (p - 1) * KB + kk;
          if (t < T) {
            const float* hrow = h0hist[t & (2 * KB - 1)];
            float ar, az, an;
            dot3(wR, wZ, wN, hrow, ar, az, an);
            if (upd) {
              float* sp = sihist[t & (2 * KB - 1)];
              sp[j] = bR + ar;            // bih1 outside (i-gates)
              sp[40 + j] = bZ + az;
              sp[80 + j] = bN + an;
            }
          }
        }
      }
      // ---- stage gi into LDS ----
      if (havenext && upd) {
        float (*gp)[120] = gih[(p + 1) & 1];
#pragma unroll
        for (int kk = 0; kk < KB; ++kk) {
          gp[kk][j] = a[kk]; gp[kk][40 + j] = c[kk]; gp[kk][80 + j] = d[kk];
        }
      }
    } else {
      // ---- h1 recurrence + output for batch p-2 (si from sihist) ----
      if (p >= 2) {
#pragma unroll
        for (int kk = 0; kk < KB; ++kk) {
          int t = (p - 2) * KB + kk;
          if (t < T) {
            const float* sp = sihist[t & (2 * KB - 1)];
            float ir = sp[j], iz = sp[40 + j], inn = sp[80 + j];
            float hr, hz, hn;
            dot3(wR, wZ, wN, h1buf, hr, hz, hn);
            float r = sigm(ir + hr + bR);
            float z = sigm(iz + hz + bZ);
            float n = tanh_fast(inn + r * (hn + bN));      // bhh1_n inside r*(.)
            h = (1.f - z) * n + z * h;
            if (upd) {
              h1buf[j] = h;
              out_cat[((size_t)b * T + t) * 80 + dir * 40 + j] = h;
            }
          }
        }
      }
    }
    __syncthreads();
  }
}

// ---------------------------------------------------------------------------
extern "C" void kernel_launch(void* const* d_in, const int* in_sizes, int n_in,
                              void* d_out, int out_size, void* d_ws, size_t ws_size,
                              hipStream_t stream) {
  const float* x        = (const float*)d_in[0];
  const float* wih_f0   = (const float*)d_in[2];
  const float* whh_f0   = (const float*)d_in[3];
  const float* bih_f0   = (const float*)d_in[4];
  const float* bhh_f0   = (const float*)d_in[5];
  const float* wih_f1   = (const float*)d_in[6];
  const float* whh_f1   = (const float*)d_in[7];
  const float* bih_f1   = (const float*)d_in[8];
  const float* bhh_f1   = (const float*)d_in[9];
  const float* wih_b0   = (const float*)d_in[10];
  const float* whh_b0   = (const float*)d_in[11];
  const float* bih_b0   = (const float*)d_in[12];
  const float* bhh_b0   = (const float*)d_in[13];
  const float* wih_b1   = (const float*)d_in[14];
  const float* whh_b1   = (const float*)d_in[15];
  const float* bih_b1   = (const float*)d_in[16];
  const float* bhh_b1   = (const float*)d_in[17];
  const float* gl_base_w   = (const float*)d_in[18];
  const float* gl_spline_w = (const float*)d_in[19];
  const float* gl_scaler   = (const float*)d_in[20];
  const float* lin_base_w   = (const float*)d_in[21];
  const float* lin_spline_w = (const float*)d_in[22];
  const float* lin_scaler   = (const float*)d_in[23];
  const float* slope        = (const float*)d_in[24];

  int B = in_sizes[1];
  int T = in_sizes[0] / (B * FIN);
  int M = B * T;

  float* Gi = (float*)d_out;   // M*240 <= M*257, overwritten by final kernel
  char* ws = (char*)d_ws;
  size_t off = 0;
  float* cat = (float*)(ws + off); off += (size_t)M * 80 * 4;
  float* U   = (float*)(ws + off); off += (size_t)M * 80 * 4;
  unsigned short* Wh_gl  = (unsigned short*)(ws + off); off += (size_t)80 * KP * 2;
  unsigned short* Wl_gl  = (unsigned short*)(ws + off); off += (size_t)80 * KP * 2;
  unsigned short* Wh_lin = (unsigned short*)(ws + off); off += (size_t)FIN * KP * 2;
  unsigned short* Wl_lin = (unsigned short*)(ws + off); off += (size_t)FIN * KP * 2;
  unsigned short* Wh_gi  = (unsigned short*)(ws + off); off += (size_t)240 * KGI * 2;
  unsigned short* Wl_gi  = (unsigned short*)(ws + off); off += (size_t)240 * KGI * 2;
  (void)ws_size; (void)n_in; (void)out_size;

  prep_wkan<<<dim3((80 * 80 + 255) / 256), 256, 0, stream>>>(gl_base_w, gl_spline_w, gl_scaler, Wh_gl, Wl_gl, 80);
  prep_wkan<<<dim3((FIN * 80 + 255) / 256), 256, 0, stream>>>(lin_base_w, lin_spline_w, lin_scaler, Wh_lin, Wl_lin, FIN);
  prep_wgi<<<dim3((240 * KGI + 255) / 256), 256, 0, stream>>>(wih_f0, wih_b0, Wh_gi, Wl_gi);

  gemm_gi_mfma<<<dim3((M + 63) / 64, 2), 256, 0, stream>>>(x, Wh_gi, Wl_gi, bih_f0, bih_b0, Gi, M);

  scan_kernel<<<dim3(2 * B), 192, 0, stream>>>(Gi,
      whh_f0, bhh_f0, wih_f1, whh_f1, bih_f1, bhh_f1,
      whh_b0, bhh_b0, wih_b1, whh_b1, bih_b1, bhh_b1,
      cat, B, T);

  kan_mfma<0><<<dim3((M + 63) / 64, 2), 256, 0, stream>>>(cat, Wh_gl, Wl_gl, nullptr, U, M, 80);
  kan_mfma<1><<<dim3((M + 63) / 64, 5), 256, 0, stream>>>(U, Wh_lin, Wl_lin, slope, (float*)d_out, M, FIN);
}

// Round 10
// 766.932 us; speedup vs baseline: 2.0305x; 1.3017x over previous
//
#include <hip/hip_runtime.h>
#include <math.h>

#define H40   40
#define NG    120
#define FIN   257
#define KP    1280     // 80 dims * 16 (silu + 8 splines + 7 pad)
#define KGI   320      // 257 padded to 5*64
#define KB    8        // scan: steps per barrier batch

typedef float  f2v  __attribute__((ext_vector_type(2)));
typedef float  f4v  __attribute__((ext_vector_type(4)));
typedef short  bfv  __attribute__((ext_vector_type(8)));
typedef unsigned short u8v __attribute__((ext_vector_type(8)));
typedef unsigned short u4v __attribute__((ext_vector_type(4)));

__device__ __forceinline__ float sigm(float x) {
  return __builtin_amdgcn_rcpf(1.0f + __expf(-x));
}
__device__ __forceinline__ float tanh_fast(float x) {
  return 1.0f - 2.0f * __builtin_amdgcn_rcpf(1.0f + __expf(2.0f * x));
}
__device__ __forceinline__ unsigned short f2bf(float x) {
  unsigned u = __float_as_uint(x);
  return (unsigned short)((u + 0x7fffu + ((u >> 16) & 1u)) >> 16);
}
__device__ __forceinline__ float bf2f(unsigned short h) {
  return __uint_as_float(((unsigned)h) << 16);
}
// packed f32x2 -> bf16x2 (RNE, identical to f2bf)
__device__ __forceinline__ unsigned cvtpk(float lo, float hi) {
  unsigned r;
  asm("v_cvt_pk_bf16_f32 %0, %1, %2" : "=v"(r) : "v"(lo), "v"(hi));
  return r;
}

// Cox-de Boor cubic B-spline bases on uniform grid g[j] = 0.4*(j-3) - 1
__device__ __forceinline__ void bspline8(float x, float* B) {
  float b0[11];
#pragma unroll
  for (int j = 0; j < 11; ++j) {
    float g0 = 0.4f * (float)(j - 3) - 1.0f;
    float g1 = 0.4f * (float)(j - 2) - 1.0f;
    b0[j] = (x >= g0 && x < g1) ? 1.0f : 0.0f;
  }
  float b1[10];
#pragma unroll
  for (int j = 0; j < 10; ++j) {
    float gj  = 0.4f * (float)(j - 3) - 1.0f;
    float gj2 = 0.4f * (float)(j - 1) - 1.0f;
    b1[j] = (x - gj) * 2.5f * b0[j] + (gj2 - x) * 2.5f * b0[j + 1];
  }
  float b2[9];
#pragma unroll
  for (int j = 0; j < 9; ++j) {
    float gj  = 0.4f * (float)(j - 3) - 1.0f;
    float gj3 = 0.4f * (float)(j)     - 1.0f;
    b2[j] = (x - gj) * 1.25f * b1[j] + (gj3 - x) * 1.25f * b1[j + 1];
  }
#pragma unroll
  for (int j = 0; j < 8; ++j) {
    float gj  = 0.4f * (float)(j - 3) - 1.0f;
    float gj4 = 0.4f * (float)(j + 1) - 1.0f;
    B[j] = (x - gj) * (1.0f / 1.2f) * b2[j] + (gj4 - x) * (1.0f / 1.2f) * b2[j + 1];
  }
}

// ---------------------------------------------------------------------------
// prep: pack KAN weights into hi/lo bf16 planes, k'' = d*16 + f
__global__ void prep_wkan(const float* __restrict__ base_w, const float* __restrict__ spline_w,
                          const float* __restrict__ scaler, unsigned short* __restrict__ Wh,
                          unsigned short* __restrict__ Wl, int N) {
  int idx = blockIdx.x * blockDim.x + threadIdx.x;
  if (idx >= N * 80) return;
  int o = idx / 80, d = idx - o * 80;
  float sc = scaler[idx];
  float vals[16];
  vals[0] = base_w[idx];
#pragma unroll
  for (int k = 0; k < 8; ++k) vals[1 + k] = spline_w[(size_t)idx * 8 + k] * sc;
#pragma unroll
  for (int k = 9; k < 16; ++k) vals[k] = 0.f;
  size_t base = (size_t)o * KP + d * 16;
#pragma unroll
  for (int f = 0; f < 16; ++f) {
    unsigned short h = f2bf(vals[f]);
    Wh[base + f] = h;
    Wl[base + f] = f2bf(vals[f] - bf2f(h));
  }
}

// prep: pack GRU input weights (fwd 0..119, bwd 120..239) into hi/lo planes, K padded 320
__global__ void prep_wgi(const float* __restrict__ wih_f0, const float* __restrict__ wih_b0,
                         unsigned short* __restrict__ Wh, unsigned short* __restrict__ Wl) {
  int idx = blockIdx.x * blockDim.x + threadIdx.x;
  if (idx >= 240 * KGI) return;
  int o = idx / KGI, k = idx - o * KGI;
  float v = 0.f;
  if (k < FIN) v = (o < NG) ? wih_f0[(size_t)o * FIN + k] : wih_b0[(size_t)(o - NG) * FIN + k];
  unsigned short h = f2bf(v);
  Wh[idx] = h;
  Wl[idx] = f2bf(v - bf2f(h));
}

// ---------------------------------------------------------------------------
// Phase A: Gi[M][240] = X[M][257] @ Wcat^T + bih, split-bf16 MFMA. BM=64, BN=128.
__global__ __launch_bounds__(256, 2) void gemm_gi_mfma(
    const float* __restrict__ X, const unsigned short* __restrict__ Wh,
    const unsigned short* __restrict__ Wl,
    const float* __restrict__ bih_f0, const float* __restrict__ bih_b0,
    float* __restrict__ Gi, int M) {
  __shared__ unsigned short Ah[64][72], Al[64][72];
  __shared__ unsigned short Bh[128][72], Bl[128][72];
  int tid = threadIdx.x;
  int m0 = blockIdx.x * 64, o0 = blockIdx.y * 128;
  int wv = tid >> 6, lane = tid & 63;
  int lr = lane & 15, lkq = lane >> 4;

  f4v acc[8];
#pragma unroll
  for (int i = 0; i < 8; ++i) acc[i] = (f4v){0.f, 0.f, 0.f, 0.f};

  for (int c = 0; c < 5; ++c) {
#pragma unroll
    for (int i = 0; i < 4; ++i) {   // A: 64 rows x 16 quad-slots
      int s = tid + i * 256;
      int rr = s >> 4, q = s & 15;
      int m = m0 + rr, k = c * 64 + q * 4;
      float v0 = 0.f, v1 = 0.f, v2 = 0.f, v3 = 0.f;
      if (m < M) {
        const float* xp = X + (size_t)m * FIN;
        if (k < FIN)     v0 = xp[k];
        if (k + 1 < FIN) v1 = xp[k + 1];
        if (k + 2 < FIN) v2 = xp[k + 2];
        if (k + 3 < FIN) v3 = xp[k + 3];
      }
      u4v h, l;
      h[0] = f2bf(v0); l[0] = f2bf(v0 - bf2f(h[0]));
      h[1] = f2bf(v1); l[1] = f2bf(v1 - bf2f(h[1]));
      h[2] = f2bf(v2); l[2] = f2bf(v2 - bf2f(h[2]));
      h[3] = f2bf(v3); l[3] = f2bf(v3 - bf2f(h[3]));
      *(u4v*)&Ah[rr][q * 4] = h;
      *(u4v*)&Al[rr][q * 4] = l;
    }
#pragma unroll
    for (int i = 0; i < 4; ++i) {   // B: 128 cols x 8 oct-slots per plane
      int s = tid + i * 256;
      int col = s >> 3, kq = s & 7;
      int o = o0 + col;
      u8v wh = 0, wl = 0;
      if (o < 240) {
        size_t base = (size_t)o * KGI + c * 64 + kq * 8;
        wh = *(const u8v*)&Wh[base];
        wl = *(const u8v*)&Wl[base];
      }
      *(u8v*)&Bh[col][kq * 8] = wh;
      *(u8v*)&Bl[col][kq * 8] = wl;
    }
    __syncthreads();
#pragma unroll
    for (int s = 0; s < 2; ++s) {
      int kl = s * 32 + lkq * 8;
      bfv a_h = *(const bfv*)&Ah[wv * 16 + lr][kl];
      bfv a_l = *(const bfv*)&Al[wv * 16 + lr][kl];
#pragma unroll
      for (int cf = 0; cf < 8; ++cf) {
        bfv b_h = *(const bfv*)&Bh[cf * 16 + lr][kl];
        bfv b_l = *(const bfv*)&Bl[cf * 16 + lr][kl];
        acc[cf] = __builtin_amdgcn_mfma_f32_16x16x32_bf16(a_h, b_l, acc[cf], 0, 0, 0);
        acc[cf] = __builtin_amdgcn_mfma_f32_16x16x32_bf16(a_l, b_h, acc[cf], 0, 0, 0);
        acc[cf] = __builtin_amdgcn_mfma_f32_16x16x32_bf16(a_h, b_h, acc[cf], 0, 0, 0);
      }
    }
    __syncthreads();
  }
#pragma unroll
  for (int cf = 0; cf < 8; ++cf) {
    int o = o0 + cf * 16 + lr;
    if (o >= 240) continue;
    float bias = (o < NG) ? bih_f0[o] : bih_b0[o - NG];
#pragma unroll
    for (int e = 0; e < 4; ++e) {
      int m = m0 + wv * 16 + lkq * 4 + e;
      if (m < M) Gi[(size_t)m * 240 + o] = acc[cf][e] + bias;
    }
  }
}

// ---------------------------------------------------------------------------
// Phase C: KAN layer, MFMA, features built on the fly. BM=64, BN=64.
// FINAL=0 (hidden): split-bf16 hi/lo, 3 MFMA per tile (U needs precision).
// FINAL=1 (output): pure bf16, 1 MFMA per tile (sigmoid compresses error).
// LDS tiles use slot-XOR swizzle slot^=(row>>3)&7 -> conflict-free writes,
// <=2-way reads (row stride 144B was an 8-way write conflict unswizzled).
template <int FINAL>
__global__ __launch_bounds__(256, 2) void kan_mfma(
    const float* __restrict__ Z, const unsigned short* __restrict__ Wh,
    const unsigned short* __restrict__ Wl, const float* __restrict__ slope,
    float* __restrict__ Y, int M, int N) {
  __shared__ float zst[80 * 64];                 // transposed z tile [d][r]
  __shared__ unsigned short Fh[64][72];
  __shared__ unsigned short Bh[64][72];
  __shared__ unsigned short Fl[FINAL ? 1 : 64][72];
  __shared__ unsigned short Bl[FINAL ? 1 : 64][72];
  int tid = threadIdx.x;
  int m0 = blockIdx.x * 64, o0 = blockIdx.y * 64;
  int wv = tid >> 6, lane = tid & 63;
  int lr = lane & 15, lkq = lane >> 4;
  int r = tid & 63, dl = tid >> 6;

#pragma unroll
  for (int i = 0; i < 5; ++i) {                  // 64 rows x 20 float4 slots
    int s = tid + i * 256;
    int rr = s / 20, q = s - rr * 20;
    float4 v = make_float4(0.f, 0.f, 0.f, 0.f);
    int m = m0 + rr;
    if (m < M) v = *(const float4*)&Z[(size_t)m * 80 + q * 4];
    zst[(q * 4 + 0) * 64 + rr] = v.x;
    zst[(q * 4 + 1) * 64 + rr] = v.y;
    zst[(q * 4 + 2) * 64 + rr] = v.z;
    zst[(q * 4 + 3) * 64 + rr] = v.w;
  }
  __syncthreads();

  f4v acc[4];
#pragma unroll
  for (int i = 0; i < 4; ++i) acc[i] = (f4v){0.f, 0.f, 0.f, 0.f};

  int sigF = (r >> 3) & 7;                       // feature-row swizzle key
  int rowA = wv * 16 + lr;
  int sigA = (rowA >> 3) & 7;

  for (int c = 0; c < 20; ++c) {
    {
      int d = c * 4 + dl;
      float z = zst[d * 64 + r];
      float f[16];
      f[0] = z * sigm(z);
      bspline8(z, &f[1]);
#pragma unroll
      for (int k = 9; k < 16; ++k) f[k] = 0.f;
      unsigned ph[8];
#pragma unroll
      for (int i2 = 0; i2 < 8; ++i2) ph[i2] = cvtpk(f[2 * i2], f[2 * i2 + 1]);
      int slot0 = (dl * 2) ^ sigF, slot1 = (dl * 2 + 1) ^ sigF;
      *(uint4*)&Fh[r][slot0 * 8] = make_uint4(ph[0], ph[1], ph[2], ph[3]);
      *(uint4*)&Fh[r][slot1 * 8] = make_uint4(ph[4], ph[5], ph[6], ph[7]);
      if (!FINAL) {
        unsigned pl[8];
#pragma unroll
        for (int i2 = 0; i2 < 8; ++i2) {
          float r0 = __uint_as_float(ph[i2] << 16);
          float r1 = __uint_as_float(ph[i2] & 0xFFFF0000u);
          pl[i2] = cvtpk(f[2 * i2] - r0, f[2 * i2 + 1] - r1);
        }
        *(uint4*)&Fl[r][slot0 * 8] = make_uint4(pl[0], pl[1], pl[2], pl[3]);
        *(uint4*)&Fl[r][slot1 * 8] = make_uint4(pl[4], pl[5], pl[6], pl[7]);
      }
    }
#pragma unroll
    for (int i = 0; i < 2; ++i) {                // W: 64 cols x 8 oct-slots
      int s = tid + i * 256;
      int col = s >> 3, kq = s & 7;
      int o = o0 + col;
      int slot = kq ^ ((col >> 3) & 7);
      u8v wh = 0, wl = 0;
      if (o < N) {
        size_t base = (size_t)o * KP + c * 64 + kq * 8;
        wh = *(const u8v*)&Wh[base];
        if (!FINAL) wl = *(const u8v*)&Wl[base];
      }
      *(u8v*)&Bh[col][slot * 8] = wh;
      if (!FINAL) *(u8v*)&Bl[col][slot * 8] = wl;
    }
    __syncthreads();
#pragma unroll
    for (int s = 0; s < 2; ++s) {
      int slotA = ((s * 4 + lkq) ^ sigA) * 8;
      bfv a_h = *(const bfv*)&Fh[rowA][slotA];
#pragma unroll
      for (int cf = 0; cf < 4; ++cf) {
        int rowB = cf * 16 + lr;
        int slotB = ((s * 4 + lkq) ^ ((rowB >> 3) & 7)) * 8;
        bfv b_h = *(const bfv*)&Bh[rowB][slotB];
        if (!FINAL) {
          bfv a_l = *(const bfv*)&Fl[rowA][slotA];
          bfv b_l = *(const bfv*)&Bl[rowB][slotB];
          acc[cf] = __builtin_amdgcn_mfma_f32_16x16x32_bf16(a_h, b_l, acc[cf], 0, 0, 0);
          acc[cf] = __builtin_amdgcn_mfma_f32_16x16x32_bf16(a_l, b_h, acc[cf], 0, 0, 0);
        }
        acc[cf] = __builtin_amdgcn_mfma_f32_16x16x32_bf16(a_h, b_h, acc[cf], 0, 0, 0);
      }
    }
    __syncthreads();
  }
#pragma unroll
  for (int cf = 0; cf < 4; ++cf) {
    int o = o0 + cf * 16 + lr;
    if (o >= N) continue;
    float sl = FINAL ? slope[o] : 0.f;
#pragma unroll
    for (int e = 0; e < 4; ++e) {
      int m = m0 + wv * 16 + lkq * 4 + e;
      if (m >= M) continue;
      float y = acc[cf][e];
      if (FINAL) y = 1.2f * sigm(sl * y);
      Y[(size_t)m * N + o] = y;
    }
  }
}

// ---------------------------------------------------------------------------
// Phase B scan helpers
__device__ __forceinline__ void load_row20(f2v* dst, const float* src) {
#pragma unroll
  for (int q = 0; q < 10; ++q) {
    f4v v = *(const f4v*)(src + 4 * q);
    dst[2 * q]     = __builtin_shufflevector(v, v, 0, 1);
    dst[2 * q + 1] = __builtin_shufflevector(v, v, 2, 3);
  }
}

__device__ __forceinline__ void dot3(const f2v* wr, const f2v* wz, const f2v* wn,
                                     const float* hrow, float& ar, float& az, float& an) {
  f2v a0 = {0.f, 0.f}, a1 = {0.f, 0.f}, a2 = {0.f, 0.f},
      a3 = {0.f, 0.f}, a4 = {0.f, 0.f}, a5 = {0.f, 0.f};
#pragma unroll
  for (int q = 0; q < 10; ++q) {
    f4v v = *(const f4v*)(hrow + 4 * q);
    f2v lo = __builtin_shufflevector(v, v, 0, 1);
    f2v hi = __builtin_shufflevector(v, v, 2, 3);
    a0 += wr[2 * q] * lo; a1 += wr[2 * q + 1] * hi;
    a2 += wz[2 * q] * lo; a3 += wz[2 * q + 1] * hi;
    a4 += wn[2 * q] * lo; a5 += wn[2 * q + 1] * hi;
  }
  ar = (a0.x + a0.y) + (a1.x + a1.y);
  az = (a2.x + a2.y) + (a3.x + a3.y);
  an = (a4.x + a4.y) + (a5.x + a5.y);
}

// Phase B: 128 chains, 3 waves/block, ONE __syncthreads per KB=8 steps.
// Each wave holds exactly ONE 120x40 weight matrix in registers (no spill):
//   wave0: whh0 -> h0 recurrence for batch p (reads gih[p&1]).
//   wave1: wih1 -> gi prefetch (batch p+1) + si = bih1 + wih1.h0 (batch p-1) -> sihist.
//   wave2: whh1 -> h1 recurrence + output (batch p-2, si from sihist).
// 16-slot histories = 2 batches so producer/consumer halves are disjoint.
__global__ __launch_bounds__(192, 1) void scan_kernel(
    const float* __restrict__ Gi,
    const float* __restrict__ whh0f, const float* __restrict__ bhh0f,
    const float* __restrict__ wih1f, const float* __restrict__ whh1f,
    const float* __restrict__ bih1f, const float* __restrict__ bhh1f,
    const float* __restrict__ whh0b, const float* __restrict__ bhh0b,
    const float* __restrict__ wih1b, const float* __restrict__ whh1b,
    const float* __restrict__ bih1b, const float* __restrict__ bhh1b,
    float* __restrict__ out_cat, int B, int T) {
  int chain = blockIdx.x;
  int dir = (chain >= B) ? 1 : 0;
  int b = chain - dir * B;

  const float* whh0 = dir ? whh0b : whh0f;
  const float* bhh0 = dir ? bhh0b : bhh0f;
  const float* wih1 = dir ? wih1b : wih1f;
  const float* whh1 = dir ? whh1b : whh1f;
  const float* bih1 = dir ? bih1b : bih1f;
  const float* bhh1 = dir ? bhh1b : bhh1f;

  __shared__ __align__(16) float h0hist[2 * KB][40];
  __shared__ __align__(16) float sihist[2 * KB][120];
  __shared__ __align__(16) float gih[2][KB][120];
  __shared__ __align__(16) float h1buf[40];

  int tid = threadIdx.x;
  int wv = tid >> 6;
  int l = tid & 63;
  bool upd = (l < 40);
  int j = upd ? l : 39;

  // ONE weight matrix per wave: w0=whh0/bhh0, w1=wih1/bih1, w2=whh1/bhh1.
  const float* wsel = (wv == 0) ? whh0 : (wv == 1) ? wih1 : whh1;
  const float* bsel = (wv == 0) ? bhh0 : (wv == 1) ? bih1 : bhh1;

  f2v wR[20], wZ[20], wN[20];
  load_row20(wR, wsel + (size_t)j * 40);
  load_row20(wZ, wsel + (size_t)(40 + j) * 40);
  load_row20(wN, wsel + (size_t)(80 + j) * 40);
  float bR = bsel[j], bZ = bsel[40 + j], bN = bsel[80 + j];

  const float* gbase = Gi + (size_t)b * T * 240 + dir * 120;
  float h = 0.f;   // wave0: h0[j]; wave2: h1[j]
  int nbatch = (T + KB - 1) / KB;

  // prologue: zero h0_{-1} slot and h1; wave1 stages gi batch 0 into gih[0]
  if (tid < 40) h0hist[2 * KB - 1][tid] = 0.f;
  if (wv == 2 && upd) h1buf[j] = 0.f;
  if (wv == 1 && upd) {
#pragma unroll
    for (int kk = 0; kk < KB; ++kk) {
      int t = kk < T ? kk : T - 1;
      int tt = dir ? (T - 1 - t) : t;
      const float* pp = gbase + (size_t)tt * 240;
      gih[0][kk][j] = pp[j];
      gih[0][kk][40 + j] = pp[40 + j];
      gih[0][kk][80 + j] = pp[80 + j];
    }
  }
  __syncthreads();

  for (int p = 0; p <= nbatch + 1; ++p) {
    if (wv == 0) {
      // ---- h0 recurrence for batch p ----
      if (p < nbatch) {
        float gr[KB], gz[KB], gn[KB];
        const float (*gp)[120] = gih[p & 1];
#pragma unroll
        for (int kk = 0; kk < KB; ++kk) {
          gr[kk] = gp[kk][j]; gz[kk] = gp[kk][40 + j]; gn[kk] = gp[kk][80 + j];
        }
#pragma unroll
        for (int kk = 0; kk < KB; ++kk) {
          int t = p * KB + kk;
          if (t < T) {
            const float* hrow = h0hist[(t + 2 * KB - 1) & (2 * KB - 1)];
            float ar, az, an;
            dot3(wR, wZ, wN, hrow, ar, az, an);
            float r = sigm(gr[kk] + bR + ar);
            float z = sigm(gz[kk] + bZ + az);
            float n = tanh_fast(gn[kk] + r * (an + bN));   // bhh0_n inside r*(.)
            h = (1.f - z) * n + z * h;
            if (upd) h0hist[t & (2 * KB - 1)][j] = h;
          }
        }
      }
    } else if (wv == 1) {
      // ---- gi prefetch (batch p+1) issued first for latency hiding ----
      float a[KB], c[KB], d[KB];
      bool havenext = (p + 1) < nbatch;
      if (havenext && upd) {
#pragma unroll
        for (int kk = 0; kk < KB; ++kk) {
          int t = (p + 1) * KB + kk; t = t < T ? t : T - 1;
          int tt = dir ? (T - 1 - t) : t;
          const float* pp = gbase + (size_t)tt * 240;
          a[kk] = pp[j]; c[kk] = pp[40 + j]; d[kk] = pp[80 + j];
        }
      }
      // ---- si for batch p-1 (h0hist written by wave0 last phase) ----
      if (p >= 1 && (p - 1) < nbatch) {
#pragma unroll
        for (int kk = 0; kk < KB; ++kk) {
          int t = (p - 1) * KB + kk;
          if (t < T) {
            const float* hrow = h0hist[t & (2 * KB - 1)];
            float ar, az, an;
            dot3(wR, wZ, wN, hrow, ar, az, an);
            if (upd) {
              float* sp = sihist[t & (2 * KB - 1)];
              sp[j] = bR + ar;            // bih1 outside (i-gates)
              sp[40 + j] = bZ + az;
              sp[80 + j] = bN + an;
            }
          }
        }
      }
      // ---- stage gi into LDS ----
      if (havenext && upd) {
        float (*gp)[120] = gih[(p + 1) & 1];
#pragma unroll
        for (int kk = 0; kk < KB; ++kk) {
          gp[kk][j] = a[kk]; gp[kk][40 + j] = c[kk]; gp[kk][80 + j] = d[kk];
        }
      }
    } else {
      // ---- h1 recurrence + output for batch p-2 (si from sihist) ----
      if (p >= 2) {
#pragma unroll
        for (int kk = 0; kk < KB; ++kk) {
          int t = (p - 2) * KB + kk;
          if (t < T) {
            const float* sp = sihist[t & (2 * KB - 1)];
            float ir = sp[j], iz = sp[40 + j], inn = sp[80 + j];
            float hr, hz, hn;
            dot3(wR, wZ, wN, h1buf, hr, hz, hn);
            float r = sigm(ir + hr + bR);
            float z = sigm(iz + hz + bZ);
            float n = tanh_fast(inn + r * (hn + bN));      // bhh1_n inside r*(.)
            h = (1.f - z) * n + z * h;
            if (upd) {
              h1buf[j] = h;
              out_cat[((size_t)b * T + t) * 80 + dir * 40 + j] = h;
            }
          }
        }
      }
    }
    __syncthreads();
  }
}

// ---------------------------------------------------------------------------
extern "C" void kernel_launch(void* const* d_in, const int* in_sizes, int n_in,
                              void* d_out, int out_size, void* d_ws, size_t ws_size,
                              hipStream_t stream) {
  const float* x        = (const float*)d_in[0];
  const float* wih_f0   = (const float*)d_in[2];
  const float* whh_f0   = (const float*)d_in[3];
  const float* bih_f0   = (const float*)d_in[4];
  const float* bhh_f0   = (const float*)d_in[5];
  const float* wih_f1   = (const float*)d_in[6];
  const float* whh_f1   = (const float*)d_in[7];
  const float* bih_f1   = (const float*)d_in[8];
  const float* bhh_f1   = (const float*)d_in[9];
  const float* wih_b0   = (const float*)d_in[10];
  const float* whh_b0   = (const float*)d_in[11];
  const float* bih_b0   = (const float*)d_in[12];
  const float* bhh_b0   = (const float*)d_in[13];
  const float* wih_b1   = (const float*)d_in[14];
  const float* whh_b1   = (const float*)d_in[15];
  const float* bih_b1   = (const float*)d_in[16];
  const float* bhh_b1   = (const float*)d_in[17];
  const float* gl_base_w   = (const float*)d_in[18];
  const float* gl_spline_w = (const float*)d_in[19];
  const float* gl_scaler   = (const float*)d_in[20];
  const float* lin_base_w   = (const float*)d_in[21];
  const float* lin_spline_w = (const float*)d_in[22];
  const float* lin_scaler   = (const float*)d_in[23];
  const float* slope        = (const float*)d_in[24];

  int B = in_sizes[1];
  int T = in_sizes[0] / (B * FIN);
  int M = B * T;

  float* Gi = (float*)d_out;   // M*240 <= M*257, overwritten by final kernel
  char* ws = (char*)d_ws;
  size_t off = 0;
  float* cat = (float*)(ws + off); off += (size_t)M * 80 * 4;
  float* U   = (float*)(ws + off); off += (size_t)M * 80 * 4;
  unsigned short* Wh_gl  = (unsigned short*)(ws + off); off += (size_t)80 * KP * 2;
  unsigned short* Wl_gl  = (unsigned short*)(ws + off); off += (size_t)80 * KP * 2;
  unsigned short* Wh_lin = (unsigned short*)(ws + off); off += (size_t)FIN * KP * 2;
  unsigned short* Wl_lin = (unsigned short*)(ws + off); off += (size_t)FIN * KP * 2;
  unsigned short* Wh_gi  = (unsigned short*)(ws + off); off += (size_t)240 * KGI * 2;
  unsigned short* Wl_gi  = (unsigned short*)(ws + off); off += (size_t)240 * KGI * 2;
  (void)ws_size; (void)n_in; (void)out_size;

  prep_wkan<<<dim3((80 * 80 + 255) / 256), 256, 0, stream>>>(gl_base_w, gl_spline_w, gl_scaler, Wh_gl, Wl_gl, 80);
  prep_wkan<<<dim3((FIN * 80 + 255) / 256), 256, 0, stream>>>(lin_base_w, lin_spline_w, lin_scaler, Wh_lin, Wl_lin, FIN);
  prep_wgi<<<dim3((240 * KGI + 255) / 256), 256, 0, stream>>>(wih_f0, wih_b0, Wh_gi, Wl_gi);

  gemm_gi_mfma<<<dim3((M + 63) / 64, 2), 256, 0, stream>>>(x, Wh_gi, Wl_gi, bih_f0, bih_b0, Gi, M);

  scan_kernel<<<dim3(2 * B), 192, 0, stream>>>(Gi,
      whh_f0, bhh_f0, wih_f1, whh_f1, bih_f1, bhh_f1,
      whh_b0, bhh_b0, wih_b1, whh_b1, bih_b1, bhh_b1,
      cat, B, T);

  kan_mfma<0><<<dim3((M + 63) / 64, 2), 256, 0, stream>>>(cat, Wh_gl, Wl_gl, nullptr, U, M, 80);
  kan_mfma<1><<<dim3((M + 63) / 64, 5), 256, 0, stream>>>(U, Wh_lin, Wl_lin, slope, (float*)d_out, M, FIN);
}

// Round 11
// 744.130 us; speedup vs baseline: 2.0928x; 1.0306x over previous
//
#include <hip/hip_runtime.h>
#include <math.h>

#define H40   40
#define NG    120
#define FIN   257
#define KP    1280     // 80 dims * 16 (silu + 8 splines + 7 pad)
#define KGI   320      // 257 padded to 5*64
#define KB    16       // scan: steps per barrier batch

typedef float  f2v  __attribute__((ext_vector_type(2)));
typedef float  f4v  __attribute__((ext_vector_type(4)));
typedef short  bfv  __attribute__((ext_vector_type(8)));
typedef unsigned short u8v __attribute__((ext_vector_type(8)));
typedef unsigned short u4v __attribute__((ext_vector_type(4)));

__device__ __forceinline__ float sigm(float x) {
  return __builtin_amdgcn_rcpf(1.0f + __expf(-x));
}
__device__ __forceinline__ float tanh_fast(float x) {
  return 1.0f - 2.0f * __builtin_amdgcn_rcpf(1.0f + __expf(2.0f * x));
}
__device__ __forceinline__ unsigned short f2bf(float x) {
  unsigned u = __float_as_uint(x);
  return (unsigned short)((u + 0x7fffu + ((u >> 16) & 1u)) >> 16);
}
__device__ __forceinline__ float bf2f(unsigned short h) {
  return __uint_as_float(((unsigned)h) << 16);
}
// packed f32x2 -> bf16x2 (RNE, identical to f2bf)
__device__ __forceinline__ unsigned cvtpk(float lo, float hi) {
  unsigned r;
  asm("v_cvt_pk_bf16_f32 %0, %1, %2" : "=v"(r) : "v"(lo), "v"(hi));
  return r;
}

// Cox-de Boor cubic B-spline bases on uniform grid g[j] = 0.4*(j-3) - 1
__device__ __forceinline__ void bspline8(float x, float* B) {
  float b0[11];
#pragma unroll
  for (int j = 0; j < 11; ++j) {
    float g0 = 0.4f * (float)(j - 3) - 1.0f;
    float g1 = 0.4f * (float)(j - 2) - 1.0f;
    b0[j] = (x >= g0 && x < g1) ? 1.0f : 0.0f;
  }
  float b1[10];
#pragma unroll
  for (int j = 0; j < 10; ++j) {
    float gj  = 0.4f * (float)(j - 3) - 1.0f;
    float gj2 = 0.4f * (float)(j - 1) - 1.0f;
    b1[j] = (x - gj) * 2.5f * b0[j] + (gj2 - x) * 2.5f * b0[j + 1];
  }
  float b2[9];
#pragma unroll
  for (int j = 0; j < 9; ++j) {
    float gj  = 0.4f * (float)(j - 3) - 1.0f;
    float gj3 = 0.4f * (float)(j)     - 1.0f;
    b2[j] = (x - gj) * 1.25f * b1[j] + (gj3 - x) * 1.25f * b1[j + 1];
  }
#pragma unroll
  for (int j = 0; j < 8; ++j) {
    float gj  = 0.4f * (float)(j - 3) - 1.0f;
    float gj4 = 0.4f * (float)(j + 1) - 1.0f;
    B[j] = (x - gj) * (1.0f / 1.2f) * b2[j] + (gj4 - x) * (1.0f / 1.2f) * b2[j + 1];
  }
}

// ---------------------------------------------------------------------------
// prep: pack KAN weights into hi/lo bf16 planes, k'' = d*16 + f
__global__ void prep_wkan(const float* __restrict__ base_w, const float* __restrict__ spline_w,
                          const float* __restrict__ scaler, unsigned short* __restrict__ Wh,
                          unsigned short* __restrict__ Wl, int N) {
  int idx = blockIdx.x * blockDim.x + threadIdx.x;
  if (idx >= N * 80) return;
  int o = idx / 80, d = idx - o * 80;
  float sc = scaler[idx];
  float vals[16];
  vals[0] = base_w[idx];
#pragma unroll
  for (int k = 0; k < 8; ++k) vals[1 + k] = spline_w[(size_t)idx * 8 + k] * sc;
#pragma unroll
  for (int k = 9; k < 16; ++k) vals[k] = 0.f;
  size_t base = (size_t)o * KP + d * 16;
#pragma unroll
  for (int f = 0; f < 16; ++f) {
    unsigned short h = f2bf(vals[f]);
    Wh[base + f] = h;
    Wl[base + f] = f2bf(vals[f] - bf2f(h));
  }
}

// prep: pack GRU input weights (fwd 0..119, bwd 120..239) into hi/lo planes, K padded 320
__global__ void prep_wgi(const float* __restrict__ wih_f0, const float* __restrict__ wih_b0,
                         unsigned short* __restrict__ Wh, unsigned short* __restrict__ Wl) {
  int idx = blockIdx.x * blockDim.x + threadIdx.x;
  if (idx >= 240 * KGI) return;
  int o = idx / KGI, k = idx - o * KGI;
  float v = 0.f;
  if (k < FIN) v = (o < NG) ? wih_f0[(size_t)o * FIN + k] : wih_b0[(size_t)(o - NG) * FIN + k];
  unsigned short h = f2bf(v);
  Wh[idx] = h;
  Wl[idx] = f2bf(v - bf2f(h));
}

// ---------------------------------------------------------------------------
// Phase A: Gi[M][240] = X[M][257] @ Wcat^T + bih, split-bf16 MFMA. BM=64, BN=128.
__global__ __launch_bounds__(256, 2) void gemm_gi_mfma(
    const float* __restrict__ X, const unsigned short* __restrict__ Wh,
    const unsigned short* __restrict__ Wl,
    const float* __restrict__ bih_f0, const float* __restrict__ bih_b0,
    float* __restrict__ Gi, int M) {
  __shared__ unsigned short Ah[64][72], Al[64][72];
  __shared__ unsigned short Bh[128][72], Bl[128][72];
  int tid = threadIdx.x;
  int m0 = blockIdx.x * 64, o0 = blockIdx.y * 128;
  int wv = tid >> 6, lane = tid & 63;
  int lr = lane & 15, lkq = lane >> 4;

  f4v acc[8];
#pragma unroll
  for (int i = 0; i < 8; ++i) acc[i] = (f4v){0.f, 0.f, 0.f, 0.f};

  for (int c = 0; c < 5; ++c) {
#pragma unroll
    for (int i = 0; i < 4; ++i) {   // A: 64 rows x 16 quad-slots
      int s = tid + i * 256;
      int rr = s >> 4, q = s & 15;
      int m = m0 + rr, k = c * 64 + q * 4;
      float v0 = 0.f, v1 = 0.f, v2 = 0.f, v3 = 0.f;
      if (m < M) {
        const float* xp = X + (size_t)m * FIN;
        if (k < FIN)     v0 = xp[k];
        if (k + 1 < FIN) v1 = xp[k + 1];
        if (k + 2 < FIN) v2 = xp[k + 2];
        if (k + 3 < FIN) v3 = xp[k + 3];
      }
      u4v h, l;
      h[0] = f2bf(v0); l[0] = f2bf(v0 - bf2f(h[0]));
      h[1] = f2bf(v1); l[1] = f2bf(v1 - bf2f(h[1]));
      h[2] = f2bf(v2); l[2] = f2bf(v2 - bf2f(h[2]));
      h[3] = f2bf(v3); l[3] = f2bf(v3 - bf2f(h[3]));
      *(u4v*)&Ah[rr][q * 4] = h;
      *(u4v*)&Al[rr][q * 4] = l;
    }
#pragma unroll
    for (int i = 0; i < 4; ++i) {   // B: 128 cols x 8 oct-slots per plane
      int s = tid + i * 256;
      int col = s >> 3, kq = s & 7;
      int o = o0 + col;
      u8v wh = 0, wl = 0;
      if (o < 240) {
        size_t base = (size_t)o * KGI + c * 64 + kq * 8;
        wh = *(const u8v*)&Wh[base];
        wl = *(const u8v*)&Wl[base];
      }
      *(u8v*)&Bh[col][kq * 8] = wh;
      *(u8v*)&Bl[col][kq * 8] = wl;
    }
    __syncthreads();
#pragma unroll
    for (int s = 0; s < 2; ++s) {
      int kl = s * 32 + lkq * 8;
      bfv a_h = *(const bfv*)&Ah[wv * 16 + lr][kl];
      bfv a_l = *(const bfv*)&Al[wv * 16 + lr][kl];
#pragma unroll
      for (int cf = 0; cf < 8; ++cf) {
        bfv b_h = *(const bfv*)&Bh[cf * 16 + lr][kl];
        bfv b_l = *(const bfv*)&Bl[cf * 16 + lr][kl];
        acc[cf] = __builtin_amdgcn_mfma_f32_16x16x32_bf16(a_h, b_l, acc[cf], 0, 0, 0);
        acc[cf] = __builtin_amdgcn_mfma_f32_16x16x32_bf16(a_l, b_h, acc[cf], 0, 0, 0);
        acc[cf] = __builtin_amdgcn_mfma_f32_16x16x32_bf16(a_h, b_h, acc[cf], 0, 0, 0);
      }
    }
    __syncthreads();
  }
#pragma unroll
  for (int cf = 0; cf < 8; ++cf) {
    int o = o0 + cf * 16 + lr;
    if (o >= 240) continue;
    float bias = (o < NG) ? bih_f0[o] : bih_b0[o - NG];
#pragma unroll
    for (int e = 0; e < 4; ++e) {
      int m = m0 + wv * 16 + lkq * 4 + e;
      if (m < M) Gi[(size_t)m * 240 + o] = acc[cf][e] + bias;
    }
  }
}

// ---------------------------------------------------------------------------
// Phase C: KAN layer, MFMA, features built on the fly. BM=64.
// Per block: features built ONCE, NCF 16-wide output tiles accumulated
// (kills the per-o-tile feature redundancy). FINAL=0: split hi/lo, 3 MFMA.
// FINAL=1: pure bf16. Slot-XOR swizzle on all tiles (conflict-free).
template <int FINAL, int NCF>
__global__ __launch_bounds__(256, 2) void kan_mfma(
    const float* __restrict__ Z, const unsigned short* __restrict__ Wh,
    const unsigned short* __restrict__ Wl, const float* __restrict__ slope,
    float* __restrict__ Y, int M, int N) {
  __shared__ float zst[80 * 64];                 // transposed z tile [d][r]
  __shared__ unsigned short Fh[64][72];
  __shared__ unsigned short Fl[FINAL ? 1 : 64][72];
  __shared__ unsigned short Bh[NCF * 16][72];
  __shared__ unsigned short Bl[FINAL ? 1 : NCF * 16][72];
  int tid = threadIdx.x;
  int m0 = blockIdx.x * 64;
  int o0 = blockIdx.y * (NCF * 16);
  int wv = tid >> 6, lane = tid & 63;
  int lr = lane & 15, lkq = lane >> 4;
  int r = tid & 63, dl = tid >> 6;

#pragma unroll
  for (int i = 0; i < 5; ++i) {                  // 64 rows x 20 float4 slots
    int s = tid + i * 256;
    int rr = s / 20, q = s - rr * 20;
    float4 v = make_float4(0.f, 0.f, 0.f, 0.f);
    int m = m0 + rr;
    if (m < M) v = *(const float4*)&Z[(size_t)m * 80 + q * 4];
    zst[(q * 4 + 0) * 64 + rr] = v.x;
    zst[(q * 4 + 1) * 64 + rr] = v.y;
    zst[(q * 4 + 2) * 64 + rr] = v.z;
    zst[(q * 4 + 3) * 64 + rr] = v.w;
  }
  __syncthreads();

  f4v acc[NCF];
#pragma unroll
  for (int i = 0; i < NCF; ++i) acc[i] = (f4v){0.f, 0.f, 0.f, 0.f};

  int sigF = (r >> 3) & 7;                       // feature-row swizzle key
  int rowA = wv * 16 + lr;
  int sigA = (rowA >> 3) & 7;

  for (int c = 0; c < 20; ++c) {
    {
      int d = c * 4 + dl;
      float z = zst[d * 64 + r];
      float f[16];
      f[0] = z * sigm(z);
      bspline8(z, &f[1]);
#pragma unroll
      for (int k = 9; k < 16; ++k) f[k] = 0.f;
      unsigned ph[8];
#pragma unroll
      for (int i2 = 0; i2 < 8; ++i2) ph[i2] = cvtpk(f[2 * i2], f[2 * i2 + 1]);
      int slot0 = (dl * 2) ^ sigF, slot1 = (dl * 2 + 1) ^ sigF;
      *(uint4*)&Fh[r][slot0 * 8] = make_uint4(ph[0], ph[1], ph[2], ph[3]);
      *(uint4*)&Fh[r][slot1 * 8] = make_uint4(ph[4], ph[5], ph[6], ph[7]);
      if (!FINAL) {
        unsigned pl[8];
#pragma unroll
        for (int i2 = 0; i2 < 8; ++i2) {
          float r0 = __uint_as_float(ph[i2] << 16);
          float r1 = __uint_as_float(ph[i2] & 0xFFFF0000u);
          pl[i2] = cvtpk(f[2 * i2] - r0, f[2 * i2 + 1] - r1);
        }
        *(uint4*)&Fl[r][slot0 * 8] = make_uint4(pl[0], pl[1], pl[2], pl[3]);
        *(uint4*)&Fl[r][slot1 * 8] = make_uint4(pl[4], pl[5], pl[6], pl[7]);
      }
    }
    for (int idx = tid; idx < NCF * 16 * 8; idx += 256) {   // W tiles
      int col = idx >> 3, kq = idx & 7;
      int o = o0 + col;
      int slot = kq ^ ((col >> 3) & 7);
      u8v wh = 0, wl = 0;
      if (o < N) {
        size_t base = (size_t)o * KP + c * 64 + kq * 8;
        wh = *(const u8v*)&Wh[base];
        if (!FINAL) wl = *(const u8v*)&Wl[base];
      }
      *(u8v*)&Bh[col][slot * 8] = wh;
      if (!FINAL) *(u8v*)&Bl[col][slot * 8] = wl;
    }
    __syncthreads();
#pragma unroll
    for (int s = 0; s < 2; ++s) {
      int slotA = ((s * 4 + lkq) ^ sigA) * 8;
      bfv a_h = *(const bfv*)&Fh[rowA][slotA];
#pragma unroll
      for (int cf = 0; cf < NCF; ++cf) {
        int rowB = cf * 16 + lr;
        int slotB = ((s * 4 + lkq) ^ ((rowB >> 3) & 7)) * 8;
        bfv b_h = *(const bfv*)&Bh[rowB][slotB];
        if (!FINAL) {
          bfv a_l = *(const bfv*)&Fl[rowA][slotA];
          bfv b_l = *(const bfv*)&Bl[rowB][slotB];
          acc[cf] = __builtin_amdgcn_mfma_f32_16x16x32_bf16(a_h, b_l, acc[cf], 0, 0, 0);
          acc[cf] = __builtin_amdgcn_mfma_f32_16x16x32_bf16(a_l, b_h, acc[cf], 0, 0, 0);
        }
        acc[cf] = __builtin_amdgcn_mfma_f32_16x16x32_bf16(a_h, b_h, acc[cf], 0, 0, 0);
      }
    }
    __syncthreads();
  }
#pragma unroll
  for (int cf = 0; cf < NCF; ++cf) {
    int o = o0 + cf * 16 + lr;
    if (o >= N) continue;
    float sl = FINAL ? slope[o] : 0.f;
#pragma unroll
    for (int e = 0; e < 4; ++e) {
      int m = m0 + wv * 16 + lkq * 4 + e;
      if (m >= M) continue;
      float y = acc[cf][e];
      if (FINAL) y = 1.2f * sigm(sl * y);
      Y[(size_t)m * N + o] = y;
    }
  }
}

// ---------------------------------------------------------------------------
// Phase B scan helpers
__device__ __forceinline__ void load_row20(f2v* dst, const float* src) {
#pragma unroll
  for (int q = 0; q < 10; ++q) {
    f4v v = *(const f4v*)(src + 4 * q);
    dst[2 * q]     = __builtin_shufflevector(v, v, 0, 1);
    dst[2 * q + 1] = __builtin_shufflevector(v, v, 2, 3);
  }
}

__device__ __forceinline__ void dot3(const f2v* wr, const f2v* wz, const f2v* wn,
                                     const float* hrow, float& ar, float& az, float& an) {
  f2v a0 = {0.f, 0.f}, a1 = {0.f, 0.f}, a2 = {0.f, 0.f},
      a3 = {0.f, 0.f}, a4 = {0.f, 0.f}, a5 = {0.f, 0.f};
#pragma unroll
  for (int q = 0; q < 10; ++q) {
    f4v v = *(const f4v*)(hrow + 4 * q);
    f2v lo = __builtin_shufflevector(v, v, 0, 1);
    f2v hi = __builtin_shufflevector(v, v, 2, 3);
    a0 += wr[2 * q] * lo; a1 += wr[2 * q + 1] * hi;
    a2 += wz[2 * q] * lo; a3 += wz[2 * q + 1] * hi;
    a4 += wn[2 * q] * lo; a5 += wn[2 * q + 1] * hi;
  }
  ar = (a0.x + a0.y) + (a1.x + a1.y);
  az = (a2.x + a2.y) + (a3.x + a3.y);
  an = (a4.x + a4.y) + (a5.x + a5.y);
}

// Phase B: 128 chains, 3 waves/block, ONE __syncthreads per KB=16 steps.
// Each wave holds exactly ONE 120x40 weight matrix in registers (no spill):
//   wave0: whh0 -> h0 recurrence for batch p (reads gih[p&1]).
//   wave1: wih1 -> gi prefetch (batch p+1) + si = bih1 + wih1.h0 (batch p-1) -> sihist.
//   wave2: whh1 -> h1 recurrence + output (batch p-2, si from sihist).
// 2*KB-slot histories = 2 batches so producer/consumer halves are disjoint.
__global__ __launch_bounds__(192, 1) void scan_kernel(
    const float* __restrict__ Gi,
    const float* __restrict__ whh0f, const float* __restrict__ bhh0f,
    const float* __restrict__ wih1f, const float* __restrict__ whh1f,
    const float* __restrict__ bih1f, const float* __restrict__ bhh1f,
    const float* __restrict__ whh0b, const float* __restrict__ bhh0b,
    const float* __restrict__ wih1b, const float* __restrict__ whh1b,
    const float* __restrict__ bih1b, const float* __restrict__ bhh1b,
    float* __restrict__ out_cat, int B, int T) {
  int chain = blockIdx.x;
  int dir = (chain >= B) ? 1 : 0;
  int b = chain - dir * B;

  const float* whh0 = dir ? whh0b : whh0f;
  const float* bhh0 = dir ? bhh0b : bhh0f;
  const float* wih1 = dir ? wih1b : wih1f;
  const float* whh1 = dir ? whh1b : whh1f;
  const float* bih1 = dir ? bih1b : bih1f;
  const float* bhh1 = dir ? bhh1b : bhh1f;

  __shared__ __align__(16) float h0hist[2 * KB][40];
  __shared__ __align__(16) float sihist[2 * KB][120];
  __shared__ __align__(16) float gih[2][KB][120];
  __shared__ __align__(16) float h1buf[40];

  int tid = threadIdx.x;
  int wv = tid >> 6;
  int l = tid & 63;
  bool upd = (l < 40);
  int j = upd ? l : 39;

  // ONE weight matrix per wave: w0=whh0/bhh0, w1=wih1/bih1, w2=whh1/bhh1.
  const float* wsel = (wv == 0) ? whh0 : (wv == 1) ? wih1 : whh1;
  const float* bsel = (wv == 0) ? bhh0 : (wv == 1) ? bih1 : bhh1;

  f2v wR[20], wZ[20], wN[20];
  load_row20(wR, wsel + (size_t)j * 40);
  load_row20(wZ, wsel + (size_t)(40 + j) * 40);
  load_row20(wN, wsel + (size_t)(80 + j) * 40);
  float bR = bsel[j], bZ = bsel[40 + j], bN = bsel[80 + j];

  const float* gbase = Gi + (size_t)b * T * 240 + dir * 120;
  float h = 0.f;   // wave0: h0[j]; wave2: h1[j]
  int nbatch = (T + KB - 1) / KB;

  // prologue: zero h0_{-1} slot and h1; wave1 stages gi batch 0 into gih[0]
  if (tid < 40) h0hist[2 * KB - 1][tid] = 0.f;
  if (wv == 2 && upd) h1buf[j] = 0.f;
  if (wv == 1 && upd) {
#pragma unroll
    for (int kk = 0; kk < KB; ++kk) {
      int t = kk < T ? kk : T - 1;
      int tt = dir ? (T - 1 - t) : t;
      const float* pp = gbase + (size_t)tt * 240;
      gih[0][kk][j] = pp[j];
      gih[0][kk][40 + j] = pp[40 + j];
      gih[0][kk][80 + j] = pp[80 + j];
    }
  }
  __syncthreads();

  for (int p = 0; p <= nbatch + 1; ++p) {
    if (wv == 0) {
      // ---- h0 recurrence for batch p ----
      if (p < nbatch) {
        const float (*gp)[120] = gih[p & 1];
#pragma unroll
        for (int kk = 0; kk < KB; ++kk) {
          int t = p * KB + kk;
          if (t < T) {
            float gr = gp[kk][j], gz = gp[kk][40 + j], gn = gp[kk][80 + j];
            const float* hrow = h0hist[(t + 2 * KB - 1) & (2 * KB - 1)];
            float ar, az, an;
            dot3(wR, wZ, wN, hrow, ar, az, an);
            float r = sigm(gr + bR + ar);
            float z = sigm(gz + bZ + az);
            float n = tanh_fast(gn + r * (an + bN));   // bhh0_n inside r*(.)
            h = (1.f - z) * n + z * h;
            if (upd) h0hist[t & (2 * KB - 1)][j] = h;
          }
        }
      }
    } else if (wv == 1) {
      // ---- gi prefetch (batch p+1) issued first for latency hiding ----
      float a[KB], c[KB], d[KB];
      bool havenext = (p + 1) < nbatch;
      if (havenext && upd) {
#pragma unroll
        for (int kk = 0; kk < KB; ++kk) {
          int t = (p + 1) * KB + kk; t = t < T ? t : T - 1;
          int tt = dir ? (T - 1 - t) : t;
          const float* pp = gbase + (size_t)tt * 240;
          a[kk] = pp[j]; c[kk] = pp[40 + j]; d[kk] = pp[80 + j];
        }
      }
      // ---- si for batch p-1 (h0hist written by wave0 last phase) ----
      if (p >= 1 && (p - 1) < nbatch) {
#pragma unroll
        for (int kk = 0; kk < KB; ++kk) {
          int t = (p - 1) * KB + kk;
          if (t < T) {
            const float* hrow = h0hist[t & (2 * KB - 1)];
            float ar, az, an;
            dot3(wR, wZ, wN, hrow, ar, az, an);
            if (upd) {
              float* sp = sihist[t & (2 * KB - 1)];
              sp[j] = bR + ar;            // bih1 outside (i-gates)
              sp[40 + j] = bZ + az;
              sp[80 + j] = bN + an;
            }
          }
        }
      }
      // ---- stage gi into LDS ----
      if (havenext && upd) {
        float (*gp)[120] = gih[(p + 1) & 1];
#pragma unroll
        for (int kk = 0; kk < KB; ++kk) {
          gp[kk][j] = a[kk]; gp[kk][40 + j] = c[kk]; gp[kk][80 + j] = d[kk];
        }
      }
    } else {
      // ---- h1 recurrence + output for batch p-2 (si from sihist) ----
      if (p >= 2) {
#pragma unroll
        for (int kk = 0; kk < KB; ++kk) {
          int t = (p - 2) * KB + kk;
          if (t < T) {
            const float* sp = sihist[t & (2 * KB - 1)];
            float ir = sp[j], iz = sp[40 + j], inn = sp[80 + j];
            float hr, hz, hn;
            dot3(wR, wZ, wN, h1buf, hr, hz, hn);
            float r = sigm(ir + hr + bR);
            float z = sigm(iz + hz + bZ);
            float n = tanh_fast(inn + r * (hn + bN));      // bhh1_n inside r*(.)
            h = (1.f - z) * n + z * h;
            if (upd) {
              h1buf[j] = h;
              out_cat[((size_t)b * T + t) * 80 + dir * 40 + j] = h;
            }
          }
        }
      }
    }
    __syncthreads();
  }
}

// ---------------------------------------------------------------------------
extern "C" void kernel_launch(void* const* d_in, const int* in_sizes, int n_in,
                              void* d_out, int out_size, void* d_ws, size_t ws_size,
                              hipStream_t stream) {
  const float* x        = (const float*)d_in[0];
  const float* wih_f0   = (const float*)d_in[2];
  const float* whh_f0   = (const float*)d_in[3];
  const float* bih_f0   = (const float*)d_in[4];
  const float* bhh_f0   = (const float*)d_in[5];
  const float* wih_f1   = (const float*)d_in[6];
  const float* whh_f1   = (const float*)d_in[7];
  const float* bih_f1   = (const float*)d_in[8];
  const float* bhh_f1   = (const float*)d_in[9];
  const float* wih_b0   = (const float*)d_in[10];
  const float* whh_b0   = (const float*)d_in[11];
  const float* bih_b0   = (const float*)d_in[12];
  const float* bhh_b0   = (const float*)d_in[13];
  const float* wih_b1   = (const float*)d_in[14];
  const float* whh_b1   = (const float*)d_in[15];
  const float* bih_b1   = (const float*)d_in[16];
  const float* bhh_b1   = (const float*)d_in[17];
  const float* gl_base_w   = (const float*)d_in[18];
  const float* gl_spline_w = (const float*)d_in[19];
  const float* gl_scaler   = (const float*)d_in[20];
  const float* lin_base_w   = (const float*)d_in[21];
  const float* lin_spline_w = (const float*)d_in[22];
  const float* lin_scaler   = (const float*)d_in[23];
  const float* slope        = (const float*)d_in[24];

  int B = in_sizes[1];
  int T = in_sizes[0] / (B * FIN);
  int M = B * T;

  float* Gi = (float*)d_out;   // M*240 <= M*257, overwritten by final kernel
  char* ws = (char*)d_ws;
  size_t off = 0;
  float* cat = (float*)(ws + off); off += (size_t)M * 80 * 4;
  float* U   = (float*)(ws + off); off += (size_t)M * 80 * 4;
  unsigned short* Wh_gl  = (unsigned short*)(ws + off); off += (size_t)80 * KP * 2;
  unsigned short* Wl_gl  = (unsigned short*)(ws + off); off += (size_t)80 * KP * 2;
  unsigned short* Wh_lin = (unsigned short*)(ws + off); off += (size_t)FIN * KP * 2;
  unsigned short* Wl_lin = (unsigned short*)(ws + off); off += (size_t)FIN * KP * 2;
  unsigned short* Wh_gi  = (unsigned short*)(ws + off); off += (size_t)240 * KGI * 2;
  unsigned short* Wl_gi  = (unsigned short*)(ws + off); off += (size_t)240 * KGI * 2;
  (void)ws_size; (void)n_in; (void)out_size;

  prep_wkan<<<dim3((80 * 80 + 255) / 256), 256, 0, stream>>>(gl_base_w, gl_spline_w, gl_scaler, Wh_gl, Wl_gl, 80);
  prep_wkan<<<dim3((FIN * 80 + 255) / 256), 256, 0, stream>>>(lin_base_w, lin_spline_w, lin_scaler, Wh_lin, Wl_lin, FIN);
  prep_wgi<<<dim3((240 * KGI + 255) / 256), 256, 0, stream>>>(wih_f0, wih_b0, Wh_gi, Wl_gi);

  gemm_gi_mfma<<<dim3((M + 63) / 64, 2), 256, 0, stream>>>(x, Wh_gi, Wl_gi, bih_f0, bih_b0, Gi, M);

  scan_kernel<<<dim3(2 * B), 192, 0, stream>>>(Gi,
      whh_f0, bhh_f0, wih_f1, whh_f1, bih_f1, bhh_f1,
      whh_b0, bhh_b0, wih_b1, whh_b1, bih_b1, bhh_b1,
      cat, B, T);

  // kan<0>: one block spans all N=80 (5 cf tiles, split hi/lo).
  kan_mfma<0, 5><<<dim3((M + 63) / 64, 1), 256, 0, stream>>>(cat, Wh_gl, Wl_gl, nullptr, U, M, 80);
  // kan<1>: two o-halves of 144 (9 cf tiles each, pure bf16).
  kan_mfma<1, 9><<<dim3((M + 63) / 64, 2), 256, 0, stream>>>(U, Wh_lin, Wl_lin, slope, (float*)d_out, M, FIN);
}

// Round 12
// 728.608 us; speedup vs baseline: 2.1373x; 1.0213x over previous
//
#include <hip/hip_runtime.h>
#include <math.h>

#define H40   40
#define NG    120
#define FIN   257
#define KP    1280     // 80 dims * 16 (silu + 8 splines + 7 pad)
#define KGI   320      // 257 padded to 5*64
#define KB    8        // scan: steps per barrier batch (16 regressed: +VGPR/+LDS, no benefit)

typedef float  f2v  __attribute__((ext_vector_type(2)));
typedef float  f4v  __attribute__((ext_vector_type(4)));
typedef short  bfv  __attribute__((ext_vector_type(8)));
typedef unsigned short u8v __attribute__((ext_vector_type(8)));
typedef unsigned short u4v __attribute__((ext_vector_type(4)));

__device__ __forceinline__ float sigm(float x) {
  return __builtin_amdgcn_rcpf(1.0f + __expf(-x));
}
__device__ __forceinline__ float tanh_fast(float x) {
  return 1.0f - 2.0f * __builtin_amdgcn_rcpf(1.0f + __expf(2.0f * x));
}
__device__ __forceinline__ unsigned short f2bf(float x) {
  unsigned u = __float_as_uint(x);
  return (unsigned short)((u + 0x7fffu + ((u >> 16) & 1u)) >> 16);
}
__device__ __forceinline__ float bf2f(unsigned short h) {
  return __uint_as_float(((unsigned)h) << 16);
}
// packed f32x2 -> bf16x2 (RNE, identical to f2bf)
__device__ __forceinline__ unsigned cvtpk(float lo, float hi) {
  unsigned r;
  asm("v_cvt_pk_bf16_f32 %0, %1, %2" : "=v"(r) : "v"(lo), "v"(hi));
  return r;
}

// Cox-de Boor cubic B-spline bases on uniform grid g[j] = 0.4*(j-3) - 1
__device__ __forceinline__ void bspline8(float x, float* B) {
  float b0[11];
#pragma unroll
  for (int j = 0; j < 11; ++j) {
    float g0 = 0.4f * (float)(j - 3) - 1.0f;
    float g1 = 0.4f * (float)(j - 2) - 1.0f;
    b0[j] = (x >= g0 && x < g1) ? 1.0f : 0.0f;
  }
  float b1[10];
#pragma unroll
  for (int j = 0; j < 10; ++j) {
    float gj  = 0.4f * (float)(j - 3) - 1.0f;
    float gj2 = 0.4f * (float)(j - 1) - 1.0f;
    b1[j] = (x - gj) * 2.5f * b0[j] + (gj2 - x) * 2.5f * b0[j + 1];
  }
  float b2[9];
#pragma unroll
  for (int j = 0; j < 9; ++j) {
    float gj  = 0.4f * (float)(j - 3) - 1.0f;
    float gj3 = 0.4f * (float)(j)     - 1.0f;
    b2[j] = (x - gj) * 1.25f * b1[j] + (gj3 - x) * 1.25f * b1[j + 1];
  }
#pragma unroll
  for (int j = 0; j < 8; ++j) {
    float gj  = 0.4f * (float)(j - 3) - 1.0f;
    float gj4 = 0.4f * (float)(j + 1) - 1.0f;
    B[j] = (x - gj) * (1.0f / 1.2f) * b2[j] + (gj4 - x) * (1.0f / 1.2f) * b2[j + 1];
  }
}

// ---------------------------------------------------------------------------
// prep: pack KAN weights into hi/lo bf16 planes, k'' = d*16 + f
__global__ void prep_wkan(const float* __restrict__ base_w, const float* __restrict__ spline_w,
                          const float* __restrict__ scaler, unsigned short* __restrict__ Wh,
                          unsigned short* __restrict__ Wl, int N) {
  int idx = blockIdx.x * blockDim.x + threadIdx.x;
  if (idx >= N * 80) return;
  int o = idx / 80, d = idx - o * 80;
  float sc = scaler[idx];
  float vals[16];
  vals[0] = base_w[idx];
#pragma unroll
  for (int k = 0; k < 8; ++k) vals[1 + k] = spline_w[(size_t)idx * 8 + k] * sc;
#pragma unroll
  for (int k = 9; k < 16; ++k) vals[k] = 0.f;
  size_t base = (size_t)o * KP + d * 16;
#pragma unroll
  for (int f = 0; f < 16; ++f) {
    unsigned short h = f2bf(vals[f]);
    Wh[base + f] = h;
    Wl[base + f] = f2bf(vals[f] - bf2f(h));
  }
}

// prep: pack GRU input weights (fwd 0..119, bwd 120..239) into hi/lo planes, K padded 320
__global__ void prep_wgi(const float* __restrict__ wih_f0, const float* __restrict__ wih_b0,
                         unsigned short* __restrict__ Wh, unsigned short* __restrict__ Wl) {
  int idx = blockIdx.x * blockDim.x + threadIdx.x;
  if (idx >= 240 * KGI) return;
  int o = idx / KGI, k = idx - o * KGI;
  float v = 0.f;
  if (k < FIN) v = (o < NG) ? wih_f0[(size_t)o * FIN + k] : wih_b0[(size_t)(o - NG) * FIN + k];
  unsigned short h = f2bf(v);
  Wh[idx] = h;
  Wl[idx] = f2bf(v - bf2f(h));
}

// ---------------------------------------------------------------------------
// Phase A: Gi[M][240] = X[M][257] @ Wcat^T + bih, split-bf16 MFMA. BM=64, BN=128.
__global__ __launch_bounds__(256, 2) void gemm_gi_mfma(
    const float* __restrict__ X, const unsigned short* __restrict__ Wh,
    const unsigned short* __restrict__ Wl,
    const float* __restrict__ bih_f0, const float* __restrict__ bih_b0,
    float* __restrict__ Gi, int M) {
  __shared__ unsigned short Ah[64][72], Al[64][72];
  __shared__ unsigned short Bh[128][72], Bl[128][72];
  int tid = threadIdx.x;
  int m0 = blockIdx.x * 64, o0 = blockIdx.y * 128;
  int wv = tid >> 6, lane = tid & 63;
  int lr = lane & 15, lkq = lane >> 4;

  f4v acc[8];
#pragma unroll
  for (int i = 0; i < 8; ++i) acc[i] = (f4v){0.f, 0.f, 0.f, 0.f};

  for (int c = 0; c < 5; ++c) {
#pragma unroll
    for (int i = 0; i < 4; ++i) {   // A: 64 rows x 16 quad-slots
      int s = tid + i * 256;
      int rr = s >> 4, q = s & 15;
      int m = m0 + rr, k = c * 64 + q * 4;
      float v0 = 0.f, v1 = 0.f, v2 = 0.f, v3 = 0.f;
      if (m < M) {
        const float* xp = X + (size_t)m * FIN;
        if (k < FIN)     v0 = xp[k];
        if (k + 1 < FIN) v1 = xp[k + 1];
        if (k + 2 < FIN) v2 = xp[k + 2];
        if (k + 3 < FIN) v3 = xp[k + 3];
      }
      u4v h, l;
      h[0] = f2bf(v0); l[0] = f2bf(v0 - bf2f(h[0]));
      h[1] = f2bf(v1); l[1] = f2bf(v1 - bf2f(h[1]));
      h[2] = f2bf(v2); l[2] = f2bf(v2 - bf2f(h[2]));
      h[3] = f2bf(v3); l[3] = f2bf(v3 - bf2f(h[3]));
      *(u4v*)&Ah[rr][q * 4] = h;
      *(u4v*)&Al[rr][q * 4] = l;
    }
#pragma unroll
    for (int i = 0; i < 4; ++i) {   // B: 128 cols x 8 oct-slots per plane
      int s = tid + i * 256;
      int col = s >> 3, kq = s & 7;
      int o = o0 + col;
      u8v wh = 0, wl = 0;
      if (o < 240) {
        size_t base = (size_t)o * KGI + c * 64 + kq * 8;
        wh = *(const u8v*)&Wh[base];
        wl = *(const u8v*)&Wl[base];
      }
      *(u8v*)&Bh[col][kq * 8] = wh;
      *(u8v*)&Bl[col][kq * 8] = wl;
    }
    __syncthreads();
#pragma unroll
    for (int s = 0; s < 2; ++s) {
      int kl = s * 32 + lkq * 8;
      bfv a_h = *(const bfv*)&Ah[wv * 16 + lr][kl];
      bfv a_l = *(const bfv*)&Al[wv * 16 + lr][kl];
#pragma unroll
      for (int cf = 0; cf < 8; ++cf) {
        bfv b_h = *(const bfv*)&Bh[cf * 16 + lr][kl];
        bfv b_l = *(const bfv*)&Bl[cf * 16 + lr][kl];
        acc[cf] = __builtin_amdgcn_mfma_f32_16x16x32_bf16(a_h, b_l, acc[cf], 0, 0, 0);
        acc[cf] = __builtin_amdgcn_mfma_f32_16x16x32_bf16(a_l, b_h, acc[cf], 0, 0, 0);
        acc[cf] = __builtin_amdgcn_mfma_f32_16x16x32_bf16(a_h, b_h, acc[cf], 0, 0, 0);
      }
    }
    __syncthreads();
  }
#pragma unroll
  for (int cf = 0; cf < 8; ++cf) {
    int o = o0 + cf * 16 + lr;
    if (o >= 240) continue;
    float bias = (o < NG) ? bih_f0[o] : bih_b0[o - NG];
#pragma unroll
    for (int e = 0; e < 4; ++e) {
      int m = m0 + wv * 16 + lkq * 4 + e;
      if (m < M) Gi[(size_t)m * 240 + o] = acc[cf][e] + bias;
    }
  }
}

// ---------------------------------------------------------------------------
// Phase C: KAN layer, MFMA, features built on the fly. BM=64.
// Per block: features built ONCE, NCF 16-wide output tiles accumulated
// (kills the per-o-tile feature redundancy). FINAL=0: split hi/lo, 3 MFMA.
// FINAL=1: pure bf16. Slot-XOR swizzle on all tiles (conflict-free).
template <int FINAL, int NCF>
__global__ __launch_bounds__(256, 2) void kan_mfma(
    const float* __restrict__ Z, const unsigned short* __restrict__ Wh,
    const unsigned short* __restrict__ Wl, const float* __restrict__ slope,
    float* __restrict__ Y, int M, int N) {
  __shared__ float zst[80 * 64];                 // transposed z tile [d][r]
  __shared__ unsigned short Fh[64][72];
  __shared__ unsigned short Fl[FINAL ? 1 : 64][72];
  __shared__ unsigned short Bh[NCF * 16][72];
  __shared__ unsigned short Bl[FINAL ? 1 : NCF * 16][72];
  int tid = threadIdx.x;
  int m0 = blockIdx.x * 64;
  int o0 = blockIdx.y * (NCF * 16);
  int wv = tid >> 6, lane = tid & 63;
  int lr = lane & 15, lkq = lane >> 4;
  int r = tid & 63, dl = tid >> 6;

#pragma unroll
  for (int i = 0; i < 5; ++i) {                  // 64 rows x 20 float4 slots
    int s = tid + i * 256;
    int rr = s / 20, q = s - rr * 20;
    float4 v = make_float4(0.f, 0.f, 0.f, 0.f);
    int m = m0 + rr;
    if (m < M) v = *(const float4*)&Z[(size_t)m * 80 + q * 4];
    zst[(q * 4 + 0) * 64 + rr] = v.x;
    zst[(q * 4 + 1) * 64 + rr] = v.y;
    zst[(q * 4 + 2) * 64 + rr] = v.z;
    zst[(q * 4 + 3) * 64 + rr] = v.w;
  }
  __syncthreads();

  f4v acc[NCF];
#pragma unroll
  for (int i = 0; i < NCF; ++i) acc[i] = (f4v){0.f, 0.f, 0.f, 0.f};

  int sigF = (r >> 3) & 7;                       // feature-row swizzle key
  int rowA = wv * 16 + lr;
  int sigA = (rowA >> 3) & 7;

  for (int c = 0; c < 20; ++c) {
    {
      int d = c * 4 + dl;
      float z = zst[d * 64 + r];
      float f[16];
      f[0] = z * sigm(z);
      bspline8(z, &f[1]);
#pragma unroll
      for (int k = 9; k < 16; ++k) f[k] = 0.f;
      unsigned ph[8];
#pragma unroll
      for (int i2 = 0; i2 < 8; ++i2) ph[i2] = cvtpk(f[2 * i2], f[2 * i2 + 1]);
      int slot0 = (dl * 2) ^ sigF, slot1 = (dl * 2 + 1) ^ sigF;
      *(uint4*)&Fh[r][slot0 * 8] = make_uint4(ph[0], ph[1], ph[2], ph[3]);
      *(uint4*)&Fh[r][slot1 * 8] = make_uint4(ph[4], ph[5], ph[6], ph[7]);
      if (!FINAL) {
        unsigned pl[8];
#pragma unroll
        for (int i2 = 0; i2 < 8; ++i2) {
          float r0 = __uint_as_float(ph[i2] << 16);
          float r1 = __uint_as_float(ph[i2] & 0xFFFF0000u);
          pl[i2] = cvtpk(f[2 * i2] - r0, f[2 * i2 + 1] - r1);
        }
        *(uint4*)&Fl[r][slot0 * 8] = make_uint4(pl[0], pl[1], pl[2], pl[3]);
        *(uint4*)&Fl[r][slot1 * 8] = make_uint4(pl[4], pl[5], pl[6], pl[7]);
      }
    }
    for (int idx = tid; idx < NCF * 16 * 8; idx += 256) {   // W tiles
      int col = idx >> 3, kq = idx & 7;
      int o = o0 + col;
      int slot = kq ^ ((col >> 3) & 7);
      u8v wh = 0, wl = 0;
      if (o < N) {
        size_t base = (size_t)o * KP + c * 64 + kq * 8;
        wh = *(const u8v*)&Wh[base];
        if (!FINAL) wl = *(const u8v*)&Wl[base];
      }
      *(u8v*)&Bh[col][slot * 8] = wh;
      if (!FINAL) *(u8v*)&Bl[col][slot * 8] = wl;
    }
    __syncthreads();
#pragma unroll
    for (int s = 0; s < 2; ++s) {
      int slotA = ((s * 4 + lkq) ^ sigA) * 8;
      bfv a_h = *(const bfv*)&Fh[rowA][slotA];
#pragma unroll
      for (int cf = 0; cf < NCF; ++cf) {
        int rowB = cf * 16 + lr;
        int slotB = ((s * 4 + lkq) ^ ((rowB >> 3) & 7)) * 8;
        bfv b_h = *(const bfv*)&Bh[rowB][slotB];
        if (!FINAL) {
          bfv a_l = *(const bfv*)&Fl[rowA][slotA];
          bfv b_l = *(const bfv*)&Bl[rowB][slotB];
          acc[cf] = __builtin_amdgcn_mfma_f32_16x16x32_bf16(a_h, b_l, acc[cf], 0, 0, 0);
          acc[cf] = __builtin_amdgcn_mfma_f32_16x16x32_bf16(a_l, b_h, acc[cf], 0, 0, 0);
        }
        acc[cf] = __builtin_amdgcn_mfma_f32_16x16x32_bf16(a_h, b_h, acc[cf], 0, 0, 0);
      }
    }
    __syncthreads();
  }
#pragma unroll
  for (int cf = 0; cf < NCF; ++cf) {
    int o = o0 + cf * 16 + lr;
    if (o >= N) continue;
    float sl = FINAL ? slope[o] : 0.f;
#pragma unroll
    for (int e = 0; e < 4; ++e) {
      int m = m0 + wv * 16 + lkq * 4 + e;
      if (m >= M) continue;
      float y = acc[cf][e];
      if (FINAL) y = 1.2f * sigm(sl * y);
      Y[(size_t)m * N + o] = y;
    }
  }
}

// ---------------------------------------------------------------------------
// Phase B scan helpers
__device__ __forceinline__ void load_row20(f2v* dst, const float* src) {
#pragma unroll
  for (int q = 0; q < 10; ++q) {
    f4v v = *(const f4v*)(src + 4 * q);
    dst[2 * q]     = __builtin_shufflevector(v, v, 0, 1);
    dst[2 * q + 1] = __builtin_shufflevector(v, v, 2, 3);
  }
}

__device__ __forceinline__ void dot3(const f2v* wr, const f2v* wz, const f2v* wn,
                                     const float* hrow, float& ar, float& az, float& an) {
  f2v a0 = {0.f, 0.f}, a1 = {0.f, 0.f}, a2 = {0.f, 0.f},
      a3 = {0.f, 0.f}, a4 = {0.f, 0.f}, a5 = {0.f, 0.f};
#pragma unroll
  for (int q = 0; q < 10; ++q) {
    f4v v = *(const f4v*)(hrow + 4 * q);
    f2v lo = __builtin_shufflevector(v, v, 0, 1);
    f2v hi = __builtin_shufflevector(v, v, 2, 3);
    a0 += wr[2 * q] * lo; a1 += wr[2 * q + 1] * hi;
    a2 += wz[2 * q] * lo; a3 += wz[2 * q + 1] * hi;
    a4 += wn[2 * q] * lo; a5 += wn[2 * q + 1] * hi;
  }
  ar = (a0.x + a0.y) + (a1.x + a1.y);
  az = (a2.x + a2.y) + (a3.x + a3.y);
  an = (a4.x + a4.y) + (a5.x + a5.y);
}

// Phase B: 128 chains, 3 waves/block, ONE __syncthreads per KB=8 steps.
// Each wave holds exactly ONE 120x40 weight matrix in registers (no spill):
//   wave0: whh0 -> h0 recurrence for batch p (reads gih[p&1]).
//   wave1: wih1 -> gi prefetch (batch p+1) + si = bih1 + wih1.h0 (batch p-1) -> sihist.
//   wave2: whh1 -> h1 recurrence + output (batch p-2, si from sihist).
// 2*KB-slot histories = 2 batches so producer/consumer halves are disjoint.
__global__ __launch_bounds__(192, 1) void scan_kernel(
    const float* __restrict__ Gi,
    const float* __restrict__ whh0f, const float* __restrict__ bhh0f,
    const float* __restrict__ wih1f, const float* __restrict__ whh1f,
    const float* __restrict__ bih1f, const float* __restrict__ bhh1f,
    const float* __restrict__ whh0b, const float* __restrict__ bhh0b,
    const float* __restrict__ wih1b, const float* __restrict__ whh1b,
    const float* __restrict__ bih1b, const float* __restrict__ bhh1b,
    float* __restrict__ out_cat, int B, int T) {
  int chain = blockIdx.x;
  int dir = (chain >= B) ? 1 : 0;
  int b = chain - dir * B;

  const float* whh0 = dir ? whh0b : whh0f;
  const float* bhh0 = dir ? bhh0b : bhh0f;
  const float* wih1 = dir ? wih1b : wih1f;
  const float* whh1 = dir ? whh1b : whh1f;
  const float* bih1 = dir ? bih1b : bih1f;
  const float* bhh1 = dir ? bhh1b : bhh1f;

  __shared__ __align__(16) float h0hist[2 * KB][40];
  __shared__ __align__(16) float sihist[2 * KB][120];
  __shared__ __align__(16) float gih[2][KB][120];
  __shared__ __align__(16) float h1buf[40];

  int tid = threadIdx.x;
  int wv = tid >> 6;
  int l = tid & 63;
  bool upd = (l < 40);
  int j = upd ? l : 39;

  // ONE weight matrix per wave: w0=whh0/bhh0, w1=wih1/bih1, w2=whh1/bhh1.
  const float* wsel = (wv == 0) ? whh0 : (wv == 1) ? wih1 : whh1;
  const float* bsel = (wv == 0) ? bhh0 : (wv == 1) ? bih1 : bhh1;

  f2v wR[20], wZ[20], wN[20];
  load_row20(wR, wsel + (size_t)j * 40);
  load_row20(wZ, wsel + (size_t)(40 + j) * 40);
  load_row20(wN, wsel + (size_t)(80 + j) * 40);
  float bR = bsel[j], bZ = bsel[40 + j], bN = bsel[80 + j];

  const float* gbase = Gi + (size_t)b * T * 240 + dir * 120;
  float h = 0.f;   // wave0: h0[j]; wave2: h1[j]
  int nbatch = (T + KB - 1) / KB;

  // prologue: zero h0_{-1} slot and h1; wave1 stages gi batch 0 into gih[0]
  if (tid < 40) h0hist[2 * KB - 1][tid] = 0.f;
  if (wv == 2 && upd) h1buf[j] = 0.f;
  if (wv == 1 && upd) {
#pragma unroll
    for (int kk = 0; kk < KB; ++kk) {
      int t = kk < T ? kk : T - 1;
      int tt = dir ? (T - 1 - t) : t;
      const float* pp = gbase + (size_t)tt * 240;
      gih[0][kk][j] = pp[j];
      gih[0][kk][40 + j] = pp[40 + j];
      gih[0][kk][80 + j] = pp[80 + j];
    }
  }
  __syncthreads();

  for (int p = 0; p <= nbatch + 1; ++p) {
    if (wv == 0) {
      // ---- h0 recurrence for batch p ----
      if (p < nbatch) {
        const float (*gp)[120] = gih[p & 1];
#pragma unroll
        for (int kk = 0; kk < KB; ++kk) {
          int t = p * KB + kk;
          if (t < T) {
            float gr = gp[kk][j], gz = gp[kk][40 + j], gn = gp[kk][80 + j];
            const float* hrow = h0hist[(t + 2 * KB - 1) & (2 * KB - 1)];
            float ar, az, an;
            dot3(wR, wZ, wN, hrow, ar, az, an);
            float r = sigm(gr + bR + ar);
            float z = sigm(gz + bZ + az);
            float n = tanh_fast(gn + r * (an + bN));   // bhh0_n inside r*(.)
            h = (1.f - z) * n + z * h;
            if (upd) h0hist[t & (2 * KB - 1)][j] = h;
          }
        }
      }
    } else if (wv == 1) {
      // ---- gi prefetch (batch p+1) issued first for latency hiding ----
      float a[KB], c[KB], d[KB];
      bool havenext = (p + 1) < nbatch;
      if (havenext && upd) {
#pragma unroll
        for (int kk = 0; kk < KB; ++kk) {
          int t = (p + 1) * KB + kk; t = t < T ? t : T - 1;
          int tt = dir ? (T - 1 - t) : t;
          const float* pp = gbase + (size_t)tt * 240;
          a[kk] = pp[j]; c[kk] = pp[40 + j]; d[kk] = pp[80 + j];
        }
      }
      // ---- si for batch p-1 (h0hist written by wave0 last phase) ----
      if (p >= 1 && (p - 1) < nbatch) {
#pragma unroll
        for (int kk = 0; kk < KB; ++kk) {
          int t = (p - 1) * KB + kk;
          if (t < T) {
            const float* hrow = h0hist[t & (2 * KB - 1)];
            float ar, az, an;
            dot3(wR, wZ, wN, hrow, ar, az, an);
            if (upd) {
              float* sp = sihist[t & (2 * KB - 1)];
              sp[j] = bR + ar;            // bih1 outside (i-gates)
              sp[40 + j] = bZ + az;
              sp[80 + j] = bN + an;
            }
          }
        }
      }
      // ---- stage gi into LDS ----
      if (havenext && upd) {
        float (*gp)[120] = gih[(p + 1) & 1];
#pragma unroll
        for (int kk = 0; kk < KB; ++kk) {
          gp[kk][j] = a[kk]; gp[kk][40 + j] = c[kk]; gp[kk][80 + j] = d[kk];
        }
      }
    } else {
      // ---- h1 recurrence + output for batch p-2 (si from sihist) ----
      if (p >= 2) {
#pragma unroll
        for (int kk = 0; kk < KB; ++kk) {
          int t = (p - 2) * KB + kk;
          if (t < T) {
            const float* sp = sihist[t & (2 * KB - 1)];
            float ir = sp[j], iz = sp[40 + j], inn = sp[80 + j];
            float hr, hz, hn;
            dot3(wR, wZ, wN, h1buf, hr, hz, hn);
            float r = sigm(ir + hr + bR);
            float z = sigm(iz + hz + bZ);
            float n = tanh_fast(inn + r * (hn + bN));      // bhh1_n inside r*(.)
            h = (1.f - z) * n + z * h;
            if (upd) {
              h1buf[j] = h;
              out_cat[((size_t)b * T + t) * 80 + dir * 40 + j] = h;
            }
          }
        }
      }
    }
    __syncthreads();
  }
}

// ---------------------------------------------------------------------------
extern "C" void kernel_launch(void* const* d_in, const int* in_sizes, int n_in,
                              void* d_out, int out_size, void* d_ws, size_t ws_size,
                              hipStream_t stream) {
  const float* x        = (const float*)d_in[0];
  const float* wih_f0   = (const float*)d_in[2];
  const float* whh_f0   = (const float*)d_in[3];
  const float* bih_f0   = (const float*)d_in[4];
  const float* bhh_f0   = (const float*)d_in[5];
  const float* wih_f1   = (const float*)d_in[6];
  const float* whh_f1   = (const float*)d_in[7];
  const float* bih_f1   = (const float*)d_in[8];
  const float* bhh_f1   = (const float*)d_in[9];
  const float* wih_b0   = (const float*)d_in[10];
  const float* whh_b0   = (const float*)d_in[11];
  const float* bih_b0   = (const float*)d_in[12];
  const float* bhh_b0   = (const float*)d_in[13];
  const float* wih_b1   = (const float*)d_in[14];
  const float* whh_b1   = (const float*)d_in[15];
  const float* bih_b1   = (const float*)d_in[16];
  const float* bhh_b1   = (const float*)d_in[17];
  const float* gl_base_w   = (const float*)d_in[18];
  const float* gl_spline_w = (const float*)d_in[19];
  const float* gl_scaler   = (const float*)d_in[20];
  const float* lin_base_w   = (const float*)d_in[21];
  const float* lin_spline_w = (const float*)d_in[22];
  const float* lin_scaler   = (const float*)d_in[23];
  const float* slope        = (const float*)d_in[24];

  int B = in_sizes[1];
  int T = in_sizes[0] / (B * FIN);
  int M = B * T;

  float* Gi = (float*)d_out;   // M*240 <= M*257, overwritten by final kernel
  char* ws = (char*)d_ws;
  size_t off = 0;
  float* cat = (float*)(ws + off); off += (size_t)M * 80 * 4;
  float* U   = (float*)(ws + off); off += (size_t)M * 80 * 4;
  unsigned short* Wh_gl  = (unsigned short*)(ws + off); off += (size_t)80 * KP * 2;
  unsigned short* Wl_gl  = (unsigned short*)(ws + off); off += (size_t)80 * KP * 2;
  unsigned short* Wh_lin = (unsigned short*)(ws + off); off += (size_t)FIN * KP * 2;
  unsigned short* Wl_lin = (unsigned short*)(ws + off); off += (size_t)FIN * KP * 2;
  unsigned short* Wh_gi  = (unsigned short*)(ws + off); off += (size_t)240 * KGI * 2;
  unsigned short* Wl_gi  = (unsigned short*)(ws + off); off += (size_t)240 * KGI * 2;
  (void)ws_size; (void)n_in; (void)out_size;

  prep_wkan<<<dim3((80 * 80 + 255) / 256), 256, 0, stream>>>(gl_base_w, gl_spline_w, gl_scaler, Wh_gl, Wl_gl, 80);
  prep_wkan<<<dim3((FIN * 80 + 255) / 256), 256, 0, stream>>>(lin_base_w, lin_spline_w, lin_scaler, Wh_lin, Wl_lin, FIN);
  prep_wgi<<<dim3((240 * KGI + 255) / 256), 256, 0, stream>>>(wih_f0, wih_b0, Wh_gi, Wl_gi);

  gemm_gi_mfma<<<dim3((M + 63) / 64, 2), 256, 0, stream>>>(x, Wh_gi, Wl_gi, bih_f0, bih_b0, Gi, M);

  scan_kernel<<<dim3(2 * B), 192, 0, stream>>>(Gi,
      whh_f0, bhh_f0, wih_f1, whh_f1, bih_f1, bhh_f1,
      whh_b0, bhh_b0, wih_b1, whh_b1, bih_b1, bhh_b1,
      cat, B, T);

  // kan<0>: one block spans all N=80 (5 cf tiles, split hi/lo).
  kan_mfma<0, 5><<<dim3((M + 63) / 64, 1), 256, 0, stream>>>(cat, Wh_gl, Wl_gl, nullptr, U, M, 80);
  // kan<1>: two o-halves of 144 (9 cf tiles each, pure bf16).
  kan_mfma<1, 9><<<dim3((M + 63) / 64, 2), 256, 0, stream>>>(U, Wh_lin, Wl_lin, slope, (float*)d_out, M, FIN);
}